// Round 20
// baseline (990.374 us; speedup 1.0000x reference)
//
#include <hip/hip_runtime.h>
#include <hip/hip_bf16.h>

// ---------------------------------------------------------------------------
// VQ-VAE 3D forward (bc=16, ld=64, ne=512).  d_out = f32[9,453,568]:
//   xhat [0,8388608) | quant [8388608,9437184) | idx [9437184,9453568)
// ws (<=18,230,416 B proven): BIG [0,16,777,216) | flag | WB f32 weights+cn.
//
// Round-20 (single kernel changed: enc2):
//   * staging index math hoisted out of the ci loop (dstoff/goff/ok arrays,
//     computed once — kills the repeated /288 %288 magic-mul sequences)
//   * 2-ci-per-phase double-stage: sm[2][...] = 38 KB (still 4 blocks/CU,
//     grid-capped), 8 phases -> barriers 32->16, 2x compute per phase.
// All else identical to r18/r19 (738 us).
// ---------------------------------------------------------------------------

typedef __hip_bfloat16 bf;
__device__ inline float b2f(bf v) { return __bfloat162float(v); }

// ---------- dtype detect ------------------------------------------------------
__global__ __launch_bounds__(256) void k_detect(const unsigned short* xu, int* flag)
{
    __shared__ int cnt[256];
    int t = threadIdx.x, c = 0;
    for (int i = t; i < 4096; i += 256) {
        unsigned short v = xu[i];
        int e = (v >> 7) & 0xFF;
        if (v == 0 || (e >= 100 && e <= 140)) c++;
    }
    cnt[t] = c;
    __syncthreads();
    for (int o = 128; o > 0; o >>= 1) { if (t < o) cnt[t] += cnt[t + o]; __syncthreads(); }
    if (t == 0) *flag = (cnt[0] >= 3277) ? 1 : 0;
}

// ---------- fused param convert (13 tensors -> contiguous WB) -----------------
struct SrcPtrs { const void* p[13]; };
__global__ __launch_bounds__(256) void k_cvtall(SrcPtrs sp, float* __restrict__ WB,
                                                const int* flag)
{
    const int offs[14] = {0,1024,1040,33808,33840,164912,164976,197744,
                          328816,328848,361616,361632,362656,362657};
    int gid = blockIdx.x * 256 + threadIdx.x;
    if (gid >= 362657) return;
    int j = 0;
    #pragma unroll
    for (int s = 1; s < 13; ++s) if (gid >= offs[s]) j = s;
    int rel = gid - offs[j];
    float v = (*flag) ? b2f(((const bf*)sp.p[j])[rel])
                      : ((const float*)sp.p[j])[rel];
    WB[gid] = v;
}

// ---------- deconv weight rearrange: w[ci][co][4,4,4] -> wr[p][ci][co][8] -----
__global__ __launch_bounds__(256) void k_rearr(const float* __restrict__ w,
    float* __restrict__ wr, int Cin, int Cout)
{
    int id = blockIdx.x * 256 + threadIdx.x;
    int total = 8 * Cin * Cout * 8;
    if (id >= total) return;
    int tap = id & 7;
    int wi = tap & 1, hi = (tap >> 1) & 1, di = (tap >> 2) & 1;
    int rest = id >> 3;
    int co = rest % Cout;
    int rest2 = rest / Cout;
    int ci = rest2 % Cin;
    int p = rest2 / Cin;
    int pw = p & 1, ph = (p >> 1) & 1, pd = (p >> 2) & 1;
    wr[id] = w[(ci * Cout + co) * 64 + ((1 - pd) + 2 * di) * 16
               + ((1 - ph) + 2 * hi) * 4 + ((1 - pw) + 2 * wi)];
}

// ---------- enc1 (pair-batched): x -> h1[j], relu. grid(1024,2) ---------------
__global__ __launch_bounds__(256) void k_enc1(const void* x, const int* flag,
    long long pairOff, const float* __restrict__ w, const float* __restrict__ b,
    float* __restrict__ out)
{
    int sp = blockIdx.x * 256 + threadIdx.x;
    int j = blockIdx.y;
    int ow = sp & 63, oh = (sp >> 6) & 63, od = sp >> 12;
    const int isBf = *flag;
    const long long nOff = pairOff + (long long)j * 2097152;
    const bf*    xb = (const bf*)x + nOff;
    const float* xf = (const float*)x + nOff;

    float v[64];
    #pragma unroll
    for (int kd = 0; kd < 4; ++kd) {
        int id = 2 * od - 1 + kd;
        #pragma unroll
        for (int kh = 0; kh < 4; ++kh) {
            int ih = 2 * oh - 1 + kh;
            #pragma unroll
            for (int kw = 0; kw < 4; ++kw) {
                int iw = 2 * ow - 1 + kw;
                bool ok = (unsigned)id < 128u && (unsigned)ih < 128u && (unsigned)iw < 128u;
                long long idx = ((long long)(ok ? id : 0) * 128 + (ok ? ih : 0)) * 128 + (ok ? iw : 0);
                float val = isBf ? b2f(xb[idx]) : xf[idx];
                v[kd * 16 + kh * 4 + kw] = ok ? val : 0.f;
            }
        }
    }
    float* on = out + (size_t)j * 4194304 + sp;
    #pragma unroll
    for (int co = 0; co < 16; ++co) {
        float acc = b[co];
        const float* wp = w + co * 64;
        #pragma unroll
        for (int t = 0; t < 64; ++t) acc += v[t] * wp[t];
        on[(long long)co * 262144] = fmaxf(acc, 0.f);
    }
}

// ---------- enc2: pair-batched, 2-ci phases, hoisted staging. grid(128,4,2) ---
__global__ __launch_bounds__(256) void k_enc2(const float* __restrict__ in,
    const float* __restrict__ w, const float* __restrict__ b,
    float* __restrict__ out)
{
    __shared__ __align__(16) float sm[2][4][18][66];   // 38,016 B; stride 66
    const int t = threadIdx.x;
    const int ow = t & 31, ohl = t >> 5;
    const int od = blockIdx.x >> 2;
    const int oh0 = (blockIdx.x & 3) * 8;
    const int cog = blockIdx.y;                  // 4 groups of 8 co
    const int j = blockIdx.z;                    // sample within pair

    { float* s = &sm[0][0][0][0];
      for (int i = t; i < 2 * 4 * 18 * 66; i += 256) s[i] = 0.f; }

    // ---- hoisted staging descriptors (ci-invariant) ----
    int  dstoff[5]; int goff[5]; bool use[5]; bool okb[5];
    #pragma unroll
    for (int r = 0; r < 5; ++r) {
        int q = r * 256 + t;
        use[r] = (q < 1152);
        int kd = q / 288, rem = q % 288;
        int rr = rem / 16, c4 = rem % 16;
        int id = 2 * od - 1 + kd;
        int ih = 2 * oh0 - 1 + rr;
        okb[r] = use[r] && (unsigned)id < 64u && (unsigned)ih < 64u;
        goff[r] = (okb[r] ? (id * 4096 + ih * 64 + c4 * 4) : 0);
        dstoff[r] = use[r] ? ((kd * 18 + rr) * 66 + c4 * 4 + 1) : 0;
    }

    float acc[8];
    #pragma unroll
    for (int u = 0; u < 8; ++u) acc[u] = b[cog * 8 + u];
    const float* gin = in + (size_t)j * 4194304;
    const float* wb = w + (size_t)(cog * 8) * 1024;   // (co*16+ci)*64

    float4 pref[2][5];
    auto LOADPH = [&](int p) {
        #pragma unroll
        for (int cc = 0; cc < 2; ++cc) {
            const float* gci = gin + (size_t)(2 * p + cc) * 262144;
            #pragma unroll
            for (int r = 0; r < 5; ++r) {
                float4 v4 = {0.f, 0.f, 0.f, 0.f};
                if (okb[r])
                    v4 = *reinterpret_cast<const float4*>(gci + goff[r]);
                pref[cc][r] = v4;
            }
        }
    };

    LOADPH(0);
    for (int p = 0; p < 8; ++p) {
        __syncthreads();                       // prior compute done reading sm
        #pragma unroll
        for (int cc = 0; cc < 2; ++cc)
            #pragma unroll
            for (int r = 0; r < 5; ++r)
                if (use[r]) {
                    float* dst = &sm[cc][0][0][0] + dstoff[r];
                    dst[0] = pref[cc][r].x; dst[1] = pref[cc][r].y;
                    dst[2] = pref[cc][r].z; dst[3] = pref[cc][r].w;
                }
        __syncthreads();                       // sm ready
        if (p + 1 < 8) LOADPH(p + 1);          // loads fly over 2-ci compute
        #pragma unroll
        for (int cc = 0; cc < 2; ++cc) {
            const int ci = 2 * p + cc;
            const float* wp = wb + ci * 64;
            #pragma unroll
            for (int kd = 0; kd < 4; ++kd)
                #pragma unroll
                for (int kh = 0; kh < 4; ++kh) {
                    const float* row = &sm[cc][kd][2 * ohl + kh][2 * ow];
                    float2 r0 = *reinterpret_cast<const float2*>(row);
                    float2 r1 = *reinterpret_cast<const float2*>(row + 2);
                    float lv[4] = {r0.x, r0.y, r1.x, r1.y};
                    #pragma unroll
                    for (int kw = 0; kw < 4; ++kw) {
                        int tap = kd * 16 + kh * 4 + kw;
                        #pragma unroll
                        for (int u = 0; u < 8; ++u)
                            acc[u] += lv[kw] * wp[u * 1024 + tap];
                    }
                }
        }
    }

    float* on = out + (size_t)j * 1048576 + (size_t)od * 1024 + (oh0 + ohl) * 32 + ow;
    #pragma unroll
    for (int u = 0; u < 8; ++u)
        on[(size_t)(cog * 8 + u) * 32768] = fmaxf(acc[u], 0.f);
}

// ---------- enc3 (LDS stride 38, acc[4], prefetch). grid(16,16,4) -------------
__global__ __launch_bounds__(256) void k_enc3(const float* __restrict__ in,
    const float* __restrict__ w, const float* __restrict__ b,
    float* __restrict__ out)
{
    __shared__ __align__(16) float sm[4][34][38];   // stride 38 = 6 mod 32
    const int t = threadIdx.x;
    const int ow = t & 15, oh = t >> 4;
    const int od = blockIdx.x;
    const int cog = blockIdx.y;                  // 16 groups of 4 co
    const int n = blockIdx.z;

    { float* s = &sm[0][0][0];
      for (int i = t; i < 4 * 34 * 38; i += 256) s[i] = 0.f; }

    float acc[4];
    #pragma unroll
    for (int u = 0; u < 4; ++u) acc[u] = b[cog * 4 + u];
    const float* gin = in + (size_t)n * 1048576;
    const float* wb = w + (size_t)(cog * 4) * 2048;   // (co*32+ci)*64

    const int hh = t >> 3, c4 = t & 7;                // hh 0..31, c4 0..7
    float4 pref[4];
    auto LOADCI = [&](int ci) {
        const float* gci = gin + (size_t)ci * 32768;
        #pragma unroll
        for (int r = 0; r < 4; ++r) {
            int id = 2 * od - 1 + r;
            float4 v4 = {0.f, 0.f, 0.f, 0.f};
            if ((unsigned)id < 32u)
                v4 = *reinterpret_cast<const float4*>(
                    gci + (size_t)id * 1024 + hh * 32 + c4 * 4);
            pref[r] = v4;
        }
    };

    LOADCI(0);
    for (int ci = 0; ci < 32; ++ci) {
        __syncthreads();
        #pragma unroll
        for (int r = 0; r < 4; ++r) {
            float* dst = &sm[r][hh + 1][c4 * 4 + 1];
            dst[0] = pref[r].x; dst[1] = pref[r].y;
            dst[2] = pref[r].z; dst[3] = pref[r].w;
        }
        __syncthreads();
        if (ci + 1 < 32) LOADCI(ci + 1);
        const float* wp = wb + ci * 64;
        #pragma unroll
        for (int kd = 0; kd < 4; ++kd)
            #pragma unroll
            for (int kh = 0; kh < 4; ++kh) {
                const float* row = &sm[kd][2 * oh + kh][2 * ow];
                float2 r0 = *reinterpret_cast<const float2*>(row);
                float2 r1 = *reinterpret_cast<const float2*>(row + 2);
                float lv[4] = {r0.x, r0.y, r1.x, r1.y};
                #pragma unroll
                for (int kw = 0; kw < 4; ++kw) {
                    int tap = kd * 16 + kh * 4 + kw;
                    #pragma unroll
                    for (int u = 0; u < 4; ++u)
                        acc[u] += lv[kw] * wp[u * 2048 + tap];
                }
            }
    }

    float* on = out + (size_t)n * 262144 + (size_t)od * 256 + oh * 16 + ow;
    #pragma unroll
    for (int u = 0; u < 4; ++u)
        on[(size_t)(cog * 4 + u) * 4096] = acc[u];
}

// ---------- codebook norms ----------------------------------------------------
__global__ __launch_bounds__(256) void k_cnorm(const float* __restrict__ cbf,
    float* __restrict__ cn)
{
    int k = blockIdx.x * 256 + threadIdx.x;
    if (k >= 512) return;
    const float* cp = cbf + k * 64;
    float s = 0.f;
    #pragma unroll
    for (int d = 0; d < 64; ++d) s += cp[d] * cp[d];
    cn[k] = s;
}

// ---------- VQ (GEMM-tiled): 64 pos/block, argmin over 512 codes --------------
__global__ __launch_bounds__(256) void k_vq(const float* __restrict__ z,
    const float* __restrict__ cbf, const float* __restrict__ cn,
    float* __restrict__ idxf)
{
    __shared__ __align__(16) float zt[64][68];
    __shared__ __align__(16) float ct[64][68];
    __shared__ float rv[16][64];
    __shared__ int   ri[16][64];

    const int tid = threadIdx.x;
    const int tx = tid & 15, ty = tid >> 4;
    const int p0 = tx * 4, c0 = ty * 4;
    const int pos0 = blockIdx.x * 64;
    const int n = pos0 >> 12, s0 = pos0 & 4095;
    const float* zn = z + (size_t)n * 262144 + s0;

    {
        int p = tid & 63;
        #pragma unroll
        for (int r = 0; r < 16; ++r) {
            int d = (tid >> 6) + r * 4;
            zt[d][p] = zn[(size_t)d * 4096 + p];
        }
    }

    float minv[4] = {3.4e38f, 3.4e38f, 3.4e38f, 3.4e38f};
    int   mini[4] = {0, 0, 0, 0};

    for (int kt = 0; kt < 8; ++kt) {
        const int k0 = kt * 64;
        __syncthreads();
        {
            int kl = tid & 63, quad = tid >> 6;
            #pragma unroll
            for (int r = 0; r < 4; ++r) {
                int d0 = quad * 16 + r * 4;
                float4 v4 = *reinterpret_cast<const float4*>(
                    cbf + (size_t)(k0 + kl) * 64 + d0);
                ct[d0 + 0][kl] = v4.x; ct[d0 + 1][kl] = v4.y;
                ct[d0 + 2][kl] = v4.z; ct[d0 + 3][kl] = v4.w;
            }
        }
        __syncthreads();

        float acc[4][4] = {};
        #pragma unroll 8
        for (int d = 0; d < 64; ++d) {
            float4 za = *reinterpret_cast<const float4*>(&zt[d][p0]);
            float4 ca = *reinterpret_cast<const float4*>(&ct[d][c0]);
            acc[0][0] += za.x * ca.x; acc[0][1] += za.x * ca.y;
            acc[0][2] += za.x * ca.z; acc[0][3] += za.x * ca.w;
            acc[1][0] += za.y * ca.x; acc[1][1] += za.y * ca.y;
            acc[1][2] += za.y * ca.z; acc[1][3] += za.y * ca.w;
            acc[2][0] += za.z * ca.x; acc[2][1] += za.z * ca.y;
            acc[2][2] += za.z * ca.z; acc[2][3] += za.z * ca.w;
            acc[3][0] += za.w * ca.x; acc[3][1] += za.w * ca.y;
            acc[3][2] += za.w * ca.z; acc[3][3] += za.w * ca.w;
        }
        #pragma unroll
        for (int jj = 0; jj < 4; ++jj) {
            float cnv = cn[k0 + c0 + jj];
            #pragma unroll
            for (int i = 0; i < 4; ++i) {
                float d2 = cnv - 2.f * acc[i][jj];
                if (d2 < minv[i]) { minv[i] = d2; mini[i] = k0 + c0 + jj; }
            }
        }
    }

    __syncthreads();
    #pragma unroll
    for (int i = 0; i < 4; ++i) { rv[ty][p0 + i] = minv[i]; ri[ty][p0 + i] = mini[i]; }
    __syncthreads();
    if (tid < 64) {
        float bv = rv[0][tid]; int bi = ri[0][tid];
        for (int g = 1; g < 16; ++g) {
            float vv = rv[g][tid]; int ii = ri[g][tid];
            if (vv < bv || (vv == bv && ii < bi)) { bv = vv; bi = ii; }
        }
        idxf[pos0 + tid] = (float)bi;
    }
}

// ---------- gather codebook rows ----------------------------------------------
__global__ __launch_bounds__(256) void k_gather(const float* __restrict__ idxf,
    const float* __restrict__ cbf, float* __restrict__ q)
{
    long long i = (long long)blockIdx.x * 256 + threadIdx.x;   // [n][d][s]
    if (i >= 1048576LL) return;
    int s = (int)(i & 4095);
    int d = (int)((i >> 12) & 63);
    int n = (int)(i >> 18);
    int k = (int)idxf[n * 4096 + s] & 511;
    q[i] = cbf[k * 64 + d];
}

// ---------- dec1 (batched): qf32 -> g1_all, relu. grid(16,8,8) ----------------
__global__ __launch_bounds__(256) void k_dec1(const float* __restrict__ in,
    const float* __restrict__ wr, const float* __restrict__ b,
    float* __restrict__ out)
{
    const int a_w = threadIdx.x & 15;
    const int a_h = threadIdx.x >> 4;
    const int a_d = blockIdx.x;
    const int par = blockIdx.y;
    const int n   = blockIdx.z >> 1;
    const int cog = blockIdx.z & 1;
    const int pd = (par >> 2) & 1, ph = (par >> 1) & 1, pw = par & 1;

    int off[8]; float msk[8];
    #pragma unroll
    for (int di = 0; di < 2; ++di)
        #pragma unroll
        for (int hi = 0; hi < 2; ++hi)
            #pragma unroll
            for (int wi = 0; wi < 2; ++wi) {
                int tt = di * 4 + hi * 2 + wi;
                int id = a_d + pd - di; bool okd = (unsigned)id < 16u; int idc = okd ? id : 0;
                int ih = a_h + ph - hi; bool okh = (unsigned)ih < 16u; int ihc = okh ? ih : 0;
                int iw = a_w + pw - wi; bool okw = (unsigned)iw < 16u; int iwc = okw ? iw : 0;
                off[tt] = (idc * 16 + ihc) * 16 + iwc;
                msk[tt] = (okd && okh && okw) ? 1.f : 0.f;
            }

    float acc[16];
    #pragma unroll
    for (int u = 0; u < 16; ++u) acc[u] = b[cog * 16 + u];

    const float* gin = in + (size_t)n * 262144;
    const float* wp = wr + (size_t)par * 16384 + cog * 128;
    for (int ci = 0; ci < 64; ++ci) {
        const float* base = gin + (size_t)ci * 4096;
        float qv[8];
        #pragma unroll
        for (int tt = 0; tt < 8; ++tt) qv[tt] = base[off[tt]] * msk[tt];
        const float* wc = wp + (size_t)ci * 256;
        #pragma unroll
        for (int u = 0; u < 16; ++u)
            #pragma unroll
            for (int tt = 0; tt < 8; ++tt)
                acc[u] += qv[tt] * wc[u * 8 + tt];
    }

    const int od = 2 * a_d + pd, oh = 2 * a_h + ph, ow = 2 * a_w + pw;
    float* on = out + (size_t)n * 1048576 + ((size_t)od * 32 + oh) * 32 + ow;
    #pragma unroll
    for (int u = 0; u < 16; ++u)
        on[(size_t)(cog * 16 + u) * 32768] = fmaxf(acc[u], 0.f);
}

// ---------- dec2 (half-batched): g1 -> g2 bf16, relu. grid(128,8,2) -----------
__global__ __launch_bounds__(256) void k_dec2(const float* __restrict__ inBase,
    const float* __restrict__ wr, const float* __restrict__ b,
    bf* __restrict__ outBase)
{
    const int a_w = threadIdx.x & 31;
    const int a_h = ((blockIdx.x & 3) << 3) + (threadIdx.x >> 5);
    const int a_d = blockIdx.x >> 2;
    const int par = blockIdx.y;
    const int j   = blockIdx.z;
    const int pd = (par >> 2) & 1, ph = (par >> 1) & 1, pw = par & 1;

    int off[8]; float msk[8];
    #pragma unroll
    for (int di = 0; di < 2; ++di)
        #pragma unroll
        for (int hi = 0; hi < 2; ++hi)
            #pragma unroll
            for (int wi = 0; wi < 2; ++wi) {
                int tt = di * 4 + hi * 2 + wi;
                int id = a_d + pd - di; bool okd = (unsigned)id < 32u; int idc = okd ? id : 0;
                int ih = a_h + ph - hi; bool okh = (unsigned)ih < 32u; int ihc = okh ? ih : 0;
                int iw = a_w + pw - wi; bool okw = (unsigned)iw < 32u; int iwc = okw ? iw : 0;
                off[tt] = (idc * 32 + ihc) * 32 + iwc;
                msk[tt] = (okd && okh && okw) ? 1.f : 0.f;
            }

    float acc[16];
    #pragma unroll
    for (int u = 0; u < 16; ++u) acc[u] = b[u];

    const float* gin = inBase + (size_t)j * 1048576;
    const float* wp = wr + (size_t)par * 4096;
    for (int ci = 0; ci < 32; ++ci) {
        const float* base = gin + (size_t)ci * 32768;
        float qv[8];
        #pragma unroll
        for (int tt = 0; tt < 8; ++tt) qv[tt] = base[off[tt]] * msk[tt];
        const float* wc = wp + (size_t)ci * 128;
        #pragma unroll
        for (int u = 0; u < 16; ++u)
            #pragma unroll
            for (int tt = 0; tt < 8; ++tt)
                acc[u] += qv[tt] * wc[u * 8 + tt];
    }

    const int od = 2 * a_d + pd, oh = 2 * a_h + ph, ow = 2 * a_w + pw;
    bf* on = outBase + (size_t)j * 4194304 + ((size_t)od * 64 + oh) * 64 + ow;
    #pragma unroll
    for (int u = 0; u < 16; ++u)
        on[(size_t)u * 262144] = __float2bfloat16(fmaxf(acc[u], 0.f));
}

// ---------- dec3 (half-batched): g2 bf16 -> xhat, sigmoid. grid(16,64,2) ------
__global__ __launch_bounds__(256) void k_dec3(const bf* __restrict__ inBase,
    const float* __restrict__ wr, const float* __restrict__ b,
    float* __restrict__ outBase)
{
    const int a_w = threadIdx.x & 63;
    const int a_h = (blockIdx.x << 2) + (threadIdx.x >> 6);
    const int a_d = blockIdx.y;
    const int j   = blockIdx.z;

    int noff[27]; float nmsk[27];
    #pragma unroll
    for (int dd = -1; dd <= 1; ++dd)
        #pragma unroll
        for (int dh = -1; dh <= 1; ++dh)
            #pragma unroll
            for (int dw = -1; dw <= 1; ++dw) {
                int zd = a_d + dd; bool okd = (unsigned)zd < 64u; int zdc = okd ? zd : 0;
                int zh = a_h + dh; bool okh = (unsigned)zh < 64u; int zhc = okh ? zh : 0;
                int zw = a_w + dw; bool okw = (unsigned)zw < 64u; int zwc = okw ? zw : 0;
                int vi = (dd + 1) * 9 + (dh + 1) * 3 + (dw + 1);
                noff[vi] = (zdc * 64 + zhc) * 64 + zwc;
                nmsk[vi] = (okd && okh && okw) ? 1.f : 0.f;
            }

    float bias = b[0];
    float acc[8];
    #pragma unroll
    for (int p = 0; p < 8; ++p) acc[p] = bias;

    const bf* gin = inBase + (size_t)j * 4194304;
    for (int ci = 0; ci < 16; ++ci) {
        const bf* base = gin + (size_t)ci * 262144;
        float v[27];
        #pragma unroll
        for (int tt = 0; tt < 27; ++tt) v[tt] = b2f(base[noff[tt]]) * nmsk[tt];
        #pragma unroll
        for (int pd = 0; pd < 2; ++pd)
            #pragma unroll
            for (int ph = 0; ph < 2; ++ph)
                #pragma unroll
                for (int pw = 0; pw < 2; ++pw) {
                    int p = pd * 4 + ph * 2 + pw;
                    const float* wc = wr + ((size_t)p * 16 + ci) * 8;
                    #pragma unroll
                    for (int di = 0; di < 2; ++di)
                        #pragma unroll
                        for (int hi = 0; hi < 2; ++hi)
                            #pragma unroll
                            for (int wi = 0; wi < 2; ++wi) {
                                int tap = di * 4 + hi * 2 + wi;
                                int vi = (pd - di + 1) * 9 + (ph - hi + 1) * 3 + (pw - wi + 1);
                                acc[p] += v[vi] * wc[tap];
                            }
                }
    }

    float* outp = outBase + (size_t)j * 2097152;
    #pragma unroll
    for (int pd = 0; pd < 2; ++pd)
        #pragma unroll
        for (int ph = 0; ph < 2; ++ph) {
            int od = 2 * a_d + pd, oh = 2 * a_h + ph;
            float s0v = 1.f / (1.f + __expf(-acc[pd * 4 + ph * 2 + 0]));
            float s1v = 1.f / (1.f + __expf(-acc[pd * 4 + ph * 2 + 1]));
            float2 w2; w2.x = s0v; w2.y = s1v;
            *reinterpret_cast<float2*>(&outp[((size_t)od * 128 + oh) * 128 + 2 * a_w]) = w2;
        }
}

// ---------------------------------------------------------------------------
extern "C" void kernel_launch(void* const* d_in, const int* in_sizes, int n_in,
                              void* d_out, int out_size, void* d_ws, size_t ws_size,
                              hipStream_t stream)
{
    if (n_in < 14) return;

    // ---- ws (proven envelope) ----
    char* WS  = (char*)d_ws;
    char* BIG = WS;                          // [0, 16,777,216)
    int*  flag = (int*)(WS + 16777216);
    float* WB  = (float*)(WS + 16777728);
    const int O_E1W = 0;
    const int O_E1B = 1024;
    const int O_E2W = 1040;
    const int O_E2B = 33808;
    const int O_E3W = 33840;
    const int O_E3B = 164912;
    const int O_CB  = 164976;
    const int O_D1W = 197744;
    const int O_D1B = 328816;
    const int O_D2W = 328848;
    const int O_D2B = 361616;
    const int O_D3W = 361632;
    const int O_D3B = 362656;
    const int O_CN  = 362660;                // ws ends 18,230,416 B

    // ---- d_out: f32[9,453,568] ----
    float* OF = (float*)d_out;
    float* xhat  = OF;
    float* quant = OF + 8388608;
    float* idxf  = OF + 9437184;
    float* h1     = OF;                      // [0, 8388608)  encode (PAIR of samples)
    float* z_all  = OF;                      // [0, 1048576)  encode (h1 dead by enc3)
    float* g1_all = OF + 4194304;            // [4194304, 8388608) decode
    float* wr1 = OF + 8388608;
    float* wr2 = OF + 8519680;
    float* wr3 = OF + 8552448;
    float* h2_all = (float*)BIG;
    float* qf32   = (float*)BIG;
    bf*    g2     = (bf*)BIG;

    auto nb = [](long long t) { return (unsigned)((t + 255) / 256); };

    // ---- detect + convert + prep ----
    k_detect<<<dim3(1), 256, 0, stream>>>((const unsigned short*)d_in[0], flag);
    SrcPtrs sp;
    for (int i = 0; i < 13; ++i) sp.p[i] = d_in[i + 1];
    k_cvtall<<<nb(362657), 256, 0, stream>>>(sp, WB, flag);
    k_cnorm<<<dim3(2), 256, 0, stream>>>(WB + O_CB, WB + O_CN);
    k_rearr<<<dim3(512), 256, 0, stream>>>(WB + O_D1W, wr1, 64, 32);
    k_rearr<<<dim3(128), 256, 0, stream>>>(WB + O_D2W, wr2, 32, 16);
    k_rearr<<<dim3(4),   256, 0, stream>>>(WB + O_D3W, wr3, 16, 1);

    // ---- encode (pair-batched) ----
    for (int p = 0; p < 2; ++p) {
        k_enc1<<<dim3(1024, 2), 256, 0, stream>>>(d_in[0], flag,
            (long long)p * 2 * 2097152, WB + O_E1W, WB + O_E1B, h1);
        k_enc2<<<dim3(128, 4, 2), 256, 0, stream>>>(h1, WB + O_E2W, WB + O_E2B,
            h2_all + (size_t)p * 2 * 1048576);
    }
    k_enc3<<<dim3(16, 16, 4), 256, 0, stream>>>(h2_all, WB + O_E3W, WB + O_E3B, z_all);
    k_vq<<<dim3(256), 256, 0, stream>>>(z_all, WB + O_CB, WB + O_CN, idxf);

    // ---- decode ----
    k_gather<<<nb(1048576LL), 256, 0, stream>>>(idxf, WB + O_CB, qf32);
    k_dec1<<<dim3(16, 8, 8), 256, 0, stream>>>(qf32, wr1, WB + O_D1B, g1_all);
    for (int h = 0; h < 2; ++h) {
        k_dec2<<<dim3(128, 8, 2), 256, 0, stream>>>(g1_all + (size_t)h * 2097152,
            wr2, WB + O_D2B, g2);
        k_dec3<<<dim3(16, 64, 2), 256, 0, stream>>>(g2, wr3, WB + O_D3B,
            xhat + (size_t)h * 4194304);
    }

    // ---- final quant gather (overwrites wr scratch) ----
    k_gather<<<nb(1048576LL), 256, 0, stream>>>(idxf, WB + O_CB, quant);
}

// Round 21
// 842.457 us; speedup vs baseline: 1.1756x; 1.1756x over previous
//
#include <hip/hip_runtime.h>
#include <hip/hip_bf16.h>

// ---------------------------------------------------------------------------
// VQ-VAE 3D forward (bc=16, ld=64, ne=512).  d_out = f32[9,453,568]:
//   xhat [0,8388608) | quant [8388608,9437184) | idx [9437184,9453568)
// ws (<=18,230,416 B proven): BIG [0,16,777,216) | flag | WB f32 weights+cn.
//
// Round-21: (a) enc2 REVERTED to the exact r18 version (122 us/dispatch;
// r20's double-stage regressed via VGPR/LDS occupancy drop + L2 thrash —
// rule: block count / occupancy beats per-thread cleverness here).
// (b) single new lever: qf32 gather FUSED into dec1 (reads cb[idx[pos]][ci]
// directly; cb is 128 KB = cache-resident) — kills one kernel + serialization.
// ---------------------------------------------------------------------------

typedef __hip_bfloat16 bf;
__device__ inline float b2f(bf v) { return __bfloat162float(v); }

// ---------- dtype detect ------------------------------------------------------
__global__ __launch_bounds__(256) void k_detect(const unsigned short* xu, int* flag)
{
    __shared__ int cnt[256];
    int t = threadIdx.x, c = 0;
    for (int i = t; i < 4096; i += 256) {
        unsigned short v = xu[i];
        int e = (v >> 7) & 0xFF;
        if (v == 0 || (e >= 100 && e <= 140)) c++;
    }
    cnt[t] = c;
    __syncthreads();
    for (int o = 128; o > 0; o >>= 1) { if (t < o) cnt[t] += cnt[t + o]; __syncthreads(); }
    if (t == 0) *flag = (cnt[0] >= 3277) ? 1 : 0;
}

// ---------- fused param convert (13 tensors -> contiguous WB) -----------------
struct SrcPtrs { const void* p[13]; };
__global__ __launch_bounds__(256) void k_cvtall(SrcPtrs sp, float* __restrict__ WB,
                                                const int* flag)
{
    const int offs[14] = {0,1024,1040,33808,33840,164912,164976,197744,
                          328816,328848,361616,361632,362656,362657};
    int gid = blockIdx.x * 256 + threadIdx.x;
    if (gid >= 362657) return;
    int j = 0;
    #pragma unroll
    for (int s = 1; s < 13; ++s) if (gid >= offs[s]) j = s;
    int rel = gid - offs[j];
    float v = (*flag) ? b2f(((const bf*)sp.p[j])[rel])
                      : ((const float*)sp.p[j])[rel];
    WB[gid] = v;
}

// ---------- deconv weight rearrange: w[ci][co][4,4,4] -> wr[p][ci][co][8] -----
__global__ __launch_bounds__(256) void k_rearr(const float* __restrict__ w,
    float* __restrict__ wr, int Cin, int Cout)
{
    int id = blockIdx.x * 256 + threadIdx.x;
    int total = 8 * Cin * Cout * 8;
    if (id >= total) return;
    int tap = id & 7;
    int wi = tap & 1, hi = (tap >> 1) & 1, di = (tap >> 2) & 1;
    int rest = id >> 3;
    int co = rest % Cout;
    int rest2 = rest / Cout;
    int ci = rest2 % Cin;
    int p = rest2 / Cin;
    int pw = p & 1, ph = (p >> 1) & 1, pd = (p >> 2) & 1;
    wr[id] = w[(ci * Cout + co) * 64 + ((1 - pd) + 2 * di) * 16
               + ((1 - ph) + 2 * hi) * 4 + ((1 - pw) + 2 * wi)];
}

// ---------- enc1 (pair-batched): x -> h1[j], relu. grid(1024,2) ---------------
__global__ __launch_bounds__(256) void k_enc1(const void* x, const int* flag,
    long long pairOff, const float* __restrict__ w, const float* __restrict__ b,
    float* __restrict__ out)
{
    int sp = blockIdx.x * 256 + threadIdx.x;
    int j = blockIdx.y;
    int ow = sp & 63, oh = (sp >> 6) & 63, od = sp >> 12;
    const int isBf = *flag;
    const long long nOff = pairOff + (long long)j * 2097152;
    const bf*    xb = (const bf*)x + nOff;
    const float* xf = (const float*)x + nOff;

    float v[64];
    #pragma unroll
    for (int kd = 0; kd < 4; ++kd) {
        int id = 2 * od - 1 + kd;
        #pragma unroll
        for (int kh = 0; kh < 4; ++kh) {
            int ih = 2 * oh - 1 + kh;
            #pragma unroll
            for (int kw = 0; kw < 4; ++kw) {
                int iw = 2 * ow - 1 + kw;
                bool ok = (unsigned)id < 128u && (unsigned)ih < 128u && (unsigned)iw < 128u;
                long long idx = ((long long)(ok ? id : 0) * 128 + (ok ? ih : 0)) * 128 + (ok ? iw : 0);
                float val = isBf ? b2f(xb[idx]) : xf[idx];
                v[kd * 16 + kh * 4 + kw] = ok ? val : 0.f;
            }
        }
    }
    float* on = out + (size_t)j * 4194304 + sp;
    #pragma unroll
    for (int co = 0; co < 16; ++co) {
        float acc = b[co];
        const float* wp = w + co * 64;
        #pragma unroll
        for (int t = 0; t < 64; ++t) acc += v[t] * wp[t];
        on[(long long)co * 262144] = fmaxf(acc, 0.f);
    }
}

// ---------- enc2 (r18 version): pair-batched, LDS stride 66. grid(128,4,2) ----
__global__ __launch_bounds__(256) void k_enc2(const float* __restrict__ in,
    const float* __restrict__ w, const float* __restrict__ b,
    float* __restrict__ out)
{
    __shared__ __align__(16) float sm[4][18][66];   // stride 66 = 2 mod 32
    const int t = threadIdx.x;
    const int ow = t & 31, ohl = t >> 5;
    const int od = blockIdx.x >> 2;
    const int oh0 = (blockIdx.x & 3) * 8;
    const int cog = blockIdx.y;                  // 4 groups of 8 co
    const int j = blockIdx.z;                    // sample within pair

    { float* s = &sm[0][0][0];
      for (int i = t; i < 4 * 18 * 66; i += 256) s[i] = 0.f; }

    float acc[8];
    #pragma unroll
    for (int u = 0; u < 8; ++u) acc[u] = b[cog * 8 + u];
    const float* gin = in + (size_t)j * 4194304;
    const float* wb = w + (size_t)(cog * 8) * 1024;   // (co*16+ci)*64

    float4 pref[5];
    auto LOADCI = [&](int ci) {
        const float* gci = gin + (size_t)ci * 262144;
        #pragma unroll
        for (int r = 0; r < 5; ++r) {
            int q = r * 256 + t;
            float4 v4 = {0.f, 0.f, 0.f, 0.f};
            if (q < 1152) {
                int kd = q / 288, rem = q % 288;
                int rr = rem / 16, c4 = rem % 16;
                int id = 2 * od - 1 + kd;
                int ih = 2 * oh0 - 1 + rr;
                if ((unsigned)id < 64u && (unsigned)ih < 64u)
                    v4 = *reinterpret_cast<const float4*>(
                        gci + (size_t)id * 4096 + ih * 64 + c4 * 4);
            }
            pref[r] = v4;
        }
    };

    LOADCI(0);
    for (int ci = 0; ci < 16; ++ci) {
        __syncthreads();
        #pragma unroll
        for (int r = 0; r < 5; ++r) {
            int q = r * 256 + t;
            if (q < 1152) {
                int kd = q / 288, rem = q % 288;
                int rr = rem / 16, c4 = rem % 16;
                float* dst = &sm[kd][rr][c4 * 4 + 1];
                dst[0] = pref[r].x; dst[1] = pref[r].y;
                dst[2] = pref[r].z; dst[3] = pref[r].w;
            }
        }
        if (ci + 1 < 16) LOADCI(ci + 1);
        __syncthreads();
        const float* wp = wb + ci * 64;
        #pragma unroll
        for (int kd = 0; kd < 4; ++kd)
            #pragma unroll
            for (int kh = 0; kh < 4; ++kh) {
                const float* row = &sm[kd][2 * ohl + kh][2 * ow];
                float2 r0 = *reinterpret_cast<const float2*>(row);
                float2 r1 = *reinterpret_cast<const float2*>(row + 2);
                float lv[4] = {r0.x, r0.y, r1.x, r1.y};
                #pragma unroll
                for (int kw = 0; kw < 4; ++kw) {
                    int tap = kd * 16 + kh * 4 + kw;
                    #pragma unroll
                    for (int u = 0; u < 8; ++u)
                        acc[u] += lv[kw] * wp[u * 1024 + tap];
                }
            }
    }

    float* on = out + (size_t)j * 1048576 + (size_t)od * 1024 + (oh0 + ohl) * 32 + ow;
    #pragma unroll
    for (int u = 0; u < 8; ++u)
        on[(size_t)(cog * 8 + u) * 32768] = fmaxf(acc[u], 0.f);
}

// ---------- enc3 (LDS stride 38, acc[4], prefetch). grid(16,16,4) -------------
__global__ __launch_bounds__(256) void k_enc3(const float* __restrict__ in,
    const float* __restrict__ w, const float* __restrict__ b,
    float* __restrict__ out)
{
    __shared__ __align__(16) float sm[4][34][38];   // stride 38 = 6 mod 32
    const int t = threadIdx.x;
    const int ow = t & 15, oh = t >> 4;
    const int od = blockIdx.x;
    const int cog = blockIdx.y;                  // 16 groups of 4 co
    const int n = blockIdx.z;

    { float* s = &sm[0][0][0];
      for (int i = t; i < 4 * 34 * 38; i += 256) s[i] = 0.f; }

    float acc[4];
    #pragma unroll
    for (int u = 0; u < 4; ++u) acc[u] = b[cog * 4 + u];
    const float* gin = in + (size_t)n * 1048576;
    const float* wb = w + (size_t)(cog * 4) * 2048;   // (co*32+ci)*64

    const int hh = t >> 3, c4 = t & 7;                // hh 0..31, c4 0..7
    float4 pref[4];
    auto LOADCI = [&](int ci) {
        const float* gci = gin + (size_t)ci * 32768;
        #pragma unroll
        for (int r = 0; r < 4; ++r) {
            int id = 2 * od - 1 + r;
            float4 v4 = {0.f, 0.f, 0.f, 0.f};
            if ((unsigned)id < 32u)
                v4 = *reinterpret_cast<const float4*>(
                    gci + (size_t)id * 1024 + hh * 32 + c4 * 4);
            pref[r] = v4;
        }
    };

    LOADCI(0);
    for (int ci = 0; ci < 32; ++ci) {
        __syncthreads();
        #pragma unroll
        for (int r = 0; r < 4; ++r) {
            float* dst = &sm[r][hh + 1][c4 * 4 + 1];
            dst[0] = pref[r].x; dst[1] = pref[r].y;
            dst[2] = pref[r].z; dst[3] = pref[r].w;
        }
        if (ci + 1 < 32) LOADCI(ci + 1);
        __syncthreads();
        const float* wp = wb + ci * 64;
        #pragma unroll
        for (int kd = 0; kd < 4; ++kd)
            #pragma unroll
            for (int kh = 0; kh < 4; ++kh) {
                const float* row = &sm[kd][2 * oh + kh][2 * ow];
                float2 r0 = *reinterpret_cast<const float2*>(row);
                float2 r1 = *reinterpret_cast<const float2*>(row + 2);
                float lv[4] = {r0.x, r0.y, r1.x, r1.y};
                #pragma unroll
                for (int kw = 0; kw < 4; ++kw) {
                    int tap = kd * 16 + kh * 4 + kw;
                    #pragma unroll
                    for (int u = 0; u < 4; ++u)
                        acc[u] += lv[kw] * wp[u * 2048 + tap];
                }
            }
    }

    float* on = out + (size_t)n * 262144 + (size_t)od * 256 + oh * 16 + ow;
    #pragma unroll
    for (int u = 0; u < 4; ++u)
        on[(size_t)(cog * 4 + u) * 4096] = acc[u];
}

// ---------- codebook norms ----------------------------------------------------
__global__ __launch_bounds__(256) void k_cnorm(const float* __restrict__ cbf,
    float* __restrict__ cn)
{
    int k = blockIdx.x * 256 + threadIdx.x;
    if (k >= 512) return;
    const float* cp = cbf + k * 64;
    float s = 0.f;
    #pragma unroll
    for (int d = 0; d < 64; ++d) s += cp[d] * cp[d];
    cn[k] = s;
}

// ---------- VQ (GEMM-tiled): 64 pos/block, argmin over 512 codes --------------
__global__ __launch_bounds__(256) void k_vq(const float* __restrict__ z,
    const float* __restrict__ cbf, const float* __restrict__ cn,
    float* __restrict__ idxf)
{
    __shared__ __align__(16) float zt[64][68];
    __shared__ __align__(16) float ct[64][68];
    __shared__ float rv[16][64];
    __shared__ int   ri[16][64];

    const int tid = threadIdx.x;
    const int tx = tid & 15, ty = tid >> 4;
    const int p0 = tx * 4, c0 = ty * 4;
    const int pos0 = blockIdx.x * 64;
    const int n = pos0 >> 12, s0 = pos0 & 4095;
    const float* zn = z + (size_t)n * 262144 + s0;

    {
        int p = tid & 63;
        #pragma unroll
        for (int r = 0; r < 16; ++r) {
            int d = (tid >> 6) + r * 4;
            zt[d][p] = zn[(size_t)d * 4096 + p];
        }
    }

    float minv[4] = {3.4e38f, 3.4e38f, 3.4e38f, 3.4e38f};
    int   mini[4] = {0, 0, 0, 0};

    for (int kt = 0; kt < 8; ++kt) {
        const int k0 = kt * 64;
        __syncthreads();
        {
            int kl = tid & 63, quad = tid >> 6;
            #pragma unroll
            for (int r = 0; r < 4; ++r) {
                int d0 = quad * 16 + r * 4;
                float4 v4 = *reinterpret_cast<const float4*>(
                    cbf + (size_t)(k0 + kl) * 64 + d0);
                ct[d0 + 0][kl] = v4.x; ct[d0 + 1][kl] = v4.y;
                ct[d0 + 2][kl] = v4.z; ct[d0 + 3][kl] = v4.w;
            }
        }
        __syncthreads();

        float acc[4][4] = {};
        #pragma unroll 8
        for (int d = 0; d < 64; ++d) {
            float4 za = *reinterpret_cast<const float4*>(&zt[d][p0]);
            float4 ca = *reinterpret_cast<const float4*>(&ct[d][c0]);
            acc[0][0] += za.x * ca.x; acc[0][1] += za.x * ca.y;
            acc[0][2] += za.x * ca.z; acc[0][3] += za.x * ca.w;
            acc[1][0] += za.y * ca.x; acc[1][1] += za.y * ca.y;
            acc[1][2] += za.y * ca.z; acc[1][3] += za.y * ca.w;
            acc[2][0] += za.z * ca.x; acc[2][1] += za.z * ca.y;
            acc[2][2] += za.z * ca.z; acc[2][3] += za.z * ca.w;
            acc[3][0] += za.w * ca.x; acc[3][1] += za.w * ca.y;
            acc[3][2] += za.w * ca.z; acc[3][3] += za.w * ca.w;
        }
        #pragma unroll
        for (int jj = 0; jj < 4; ++jj) {
            float cnv = cn[k0 + c0 + jj];
            #pragma unroll
            for (int i = 0; i < 4; ++i) {
                float d2 = cnv - 2.f * acc[i][jj];
                if (d2 < minv[i]) { minv[i] = d2; mini[i] = k0 + c0 + jj; }
            }
        }
    }

    __syncthreads();
    #pragma unroll
    for (int i = 0; i < 4; ++i) { rv[ty][p0 + i] = minv[i]; ri[ty][p0 + i] = mini[i]; }
    __syncthreads();
    if (tid < 64) {
        float bv = rv[0][tid]; int bi = ri[0][tid];
        for (int g = 1; g < 16; ++g) {
            float vv = rv[g][tid]; int ii = ri[g][tid];
            if (vv < bv || (vv == bv && ii < bi)) { bv = vv; bi = ii; }
        }
        idxf[pos0 + tid] = (float)bi;
    }
}

// ---------- gather codebook rows (final quant output only) --------------------
__global__ __launch_bounds__(256) void k_gather(const float* __restrict__ idxf,
    const float* __restrict__ cbf, float* __restrict__ q)
{
    long long i = (long long)blockIdx.x * 256 + threadIdx.x;   // [n][d][s]
    if (i >= 1048576LL) return;
    int s = (int)(i & 4095);
    int d = (int)((i >> 12) & 63);
    int n = (int)(i >> 18);
    int k = (int)idxf[n * 4096 + s] & 511;
    q[i] = cbf[k * 64 + d];
}

// ---------- dec1 (fused gather): idx+cb -> g1_all, relu. grid(16,8,8) ---------
__global__ __launch_bounds__(256) void k_dec1(const float* __restrict__ idxf,
    const float* __restrict__ cbf, const float* __restrict__ wr,
    const float* __restrict__ b, float* __restrict__ out)
{
    const int a_w = threadIdx.x & 15;
    const int a_h = threadIdx.x >> 4;
    const int a_d = blockIdx.x;
    const int par = blockIdx.y;
    const int n   = blockIdx.z >> 1;
    const int cog = blockIdx.z & 1;
    const int pd = (par >> 2) & 1, ph = (par >> 1) & 1, pw = par & 1;

    int off[8]; float msk[8];
    #pragma unroll
    for (int di = 0; di < 2; ++di)
        #pragma unroll
        for (int hi = 0; hi < 2; ++hi)
            #pragma unroll
            for (int wi = 0; wi < 2; ++wi) {
                int tt = di * 4 + hi * 2 + wi;
                int id = a_d + pd - di; bool okd = (unsigned)id < 16u; int idc = okd ? id : 0;
                int ih = a_h + ph - hi; bool okh = (unsigned)ih < 16u; int ihc = okh ? ih : 0;
                int iw = a_w + pw - wi; bool okw = (unsigned)iw < 16u; int iwc = okw ? iw : 0;
                off[tt] = (idc * 16 + ihc) * 16 + iwc;
                msk[tt] = (okd && okh && okw) ? 1.f : 0.f;
            }

    // gather code ids once (cache-hot; idx is final output region)
    const float* iz = idxf + n * 4096;
    int kid[8];
    #pragma unroll
    for (int tt = 0; tt < 8; ++tt) kid[tt] = ((int)iz[off[tt]] & 511) * 64;

    float acc[16];
    #pragma unroll
    for (int u = 0; u < 16; ++u) acc[u] = b[cog * 16 + u];

    const float* wp = wr + (size_t)par * 16384 + cog * 128;
    for (int ci = 0; ci < 64; ++ci) {
        float qv[8];
        #pragma unroll
        for (int tt = 0; tt < 8; ++tt) qv[tt] = cbf[kid[tt] + ci] * msk[tt];
        const float* wc = wp + (size_t)ci * 256;
        #pragma unroll
        for (int u = 0; u < 16; ++u)
            #pragma unroll
            for (int tt = 0; tt < 8; ++tt)
                acc[u] += qv[tt] * wc[u * 8 + tt];
    }

    const int od = 2 * a_d + pd, oh = 2 * a_h + ph, ow = 2 * a_w + pw;
    float* on = out + (size_t)n * 1048576 + ((size_t)od * 32 + oh) * 32 + ow;
    #pragma unroll
    for (int u = 0; u < 16; ++u)
        on[(size_t)(cog * 16 + u) * 32768] = fmaxf(acc[u], 0.f);
}

// ---------- dec2 (half-batched): g1 -> g2 bf16, relu. grid(128,8,2) -----------
__global__ __launch_bounds__(256) void k_dec2(const float* __restrict__ inBase,
    const float* __restrict__ wr, const float* __restrict__ b,
    bf* __restrict__ outBase)
{
    const int a_w = threadIdx.x & 31;
    const int a_h = ((blockIdx.x & 3) << 3) + (threadIdx.x >> 5);
    const int a_d = blockIdx.x >> 2;
    const int par = blockIdx.y;
    const int j   = blockIdx.z;
    const int pd = (par >> 2) & 1, ph = (par >> 1) & 1, pw = par & 1;

    int off[8]; float msk[8];
    #pragma unroll
    for (int di = 0; di < 2; ++di)
        #pragma unroll
        for (int hi = 0; hi < 2; ++hi)
            #pragma unroll
            for (int wi = 0; wi < 2; ++wi) {
                int tt = di * 4 + hi * 2 + wi;
                int id = a_d + pd - di; bool okd = (unsigned)id < 32u; int idc = okd ? id : 0;
                int ih = a_h + ph - hi; bool okh = (unsigned)ih < 32u; int ihc = okh ? ih : 0;
                int iw = a_w + pw - wi; bool okw = (unsigned)iw < 32u; int iwc = okw ? iw : 0;
                off[tt] = (idc * 32 + ihc) * 32 + iwc;
                msk[tt] = (okd && okh && okw) ? 1.f : 0.f;
            }

    float acc[16];
    #pragma unroll
    for (int u = 0; u < 16; ++u) acc[u] = b[u];

    const float* gin = inBase + (size_t)j * 1048576;
    const float* wp = wr + (size_t)par * 4096;
    for (int ci = 0; ci < 32; ++ci) {
        const float* base = gin + (size_t)ci * 32768;
        float qv[8];
        #pragma unroll
        for (int tt = 0; tt < 8; ++tt) qv[tt] = base[off[tt]] * msk[tt];
        const float* wc = wp + (size_t)ci * 128;
        #pragma unroll
        for (int u = 0; u < 16; ++u)
            #pragma unroll
            for (int tt = 0; tt < 8; ++tt)
                acc[u] += qv[tt] * wc[u * 8 + tt];
    }

    const int od = 2 * a_d + pd, oh = 2 * a_h + ph, ow = 2 * a_w + pw;
    bf* on = outBase + (size_t)j * 4194304 + ((size_t)od * 64 + oh) * 64 + ow;
    #pragma unroll
    for (int u = 0; u < 16; ++u)
        on[(size_t)u * 262144] = __float2bfloat16(fmaxf(acc[u], 0.f));
}

// ---------- dec3 (half-batched): g2 bf16 -> xhat, sigmoid. grid(16,64,2) ------
__global__ __launch_bounds__(256) void k_dec3(const bf* __restrict__ inBase,
    const float* __restrict__ wr, const float* __restrict__ b,
    float* __restrict__ outBase)
{
    const int a_w = threadIdx.x & 63;
    const int a_h = (blockIdx.x << 2) + (threadIdx.x >> 6);
    const int a_d = blockIdx.y;
    const int j   = blockIdx.z;

    int noff[27]; float nmsk[27];
    #pragma unroll
    for (int dd = -1; dd <= 1; ++dd)
        #pragma unroll
        for (int dh = -1; dh <= 1; ++dh)
            #pragma unroll
            for (int dw = -1; dw <= 1; ++dw) {
                int zd = a_d + dd; bool okd = (unsigned)zd < 64u; int zdc = okd ? zd : 0;
                int zh = a_h + dh; bool okh = (unsigned)zh < 64u; int zhc = okh ? zh : 0;
                int zw = a_w + dw; bool okw = (unsigned)zw < 64u; int zwc = okw ? zw : 0;
                int vi = (dd + 1) * 9 + (dh + 1) * 3 + (dw + 1);
                noff[vi] = (zdc * 64 + zhc) * 64 + zwc;
                nmsk[vi] = (okd && okh && okw) ? 1.f : 0.f;
            }

    float bias = b[0];
    float acc[8];
    #pragma unroll
    for (int p = 0; p < 8; ++p) acc[p] = bias;

    const bf* gin = inBase + (size_t)j * 4194304;
    for (int ci = 0; ci < 16; ++ci) {
        const bf* base = gin + (size_t)ci * 262144;
        float v[27];
        #pragma unroll
        for (int tt = 0; tt < 27; ++tt) v[tt] = b2f(base[noff[tt]]) * nmsk[tt];
        #pragma unroll
        for (int pd = 0; pd < 2; ++pd)
            #pragma unroll
            for (int ph = 0; ph < 2; ++ph)
                #pragma unroll
                for (int pw = 0; pw < 2; ++pw) {
                    int p = pd * 4 + ph * 2 + pw;
                    const float* wc = wr + ((size_t)p * 16 + ci) * 8;
                    #pragma unroll
                    for (int di = 0; di < 2; ++di)
                        #pragma unroll
                        for (int hi = 0; hi < 2; ++hi)
                            #pragma unroll
                            for (int wi = 0; wi < 2; ++wi) {
                                int tap = di * 4 + hi * 2 + wi;
                                int vi = (pd - di + 1) * 9 + (ph - hi + 1) * 3 + (pw - wi + 1);
                                acc[p] += v[vi] * wc[tap];
                            }
                }
    }

    float* outp = outBase + (size_t)j * 2097152;
    #pragma unroll
    for (int pd = 0; pd < 2; ++pd)
        #pragma unroll
        for (int ph = 0; ph < 2; ++ph) {
            int od = 2 * a_d + pd, oh = 2 * a_h + ph;
            float s0v = 1.f / (1.f + __expf(-acc[pd * 4 + ph * 2 + 0]));
            float s1v = 1.f / (1.f + __expf(-acc[pd * 4 + ph * 2 + 1]));
            float2 w2; w2.x = s0v; w2.y = s1v;
            *reinterpret_cast<float2*>(&outp[((size_t)od * 128 + oh) * 128 + 2 * a_w]) = w2;
        }
}

// ---------------------------------------------------------------------------
extern "C" void kernel_launch(void* const* d_in, const int* in_sizes, int n_in,
                              void* d_out, int out_size, void* d_ws, size_t ws_size,
                              hipStream_t stream)
{
    if (n_in < 14) return;

    // ---- ws (proven envelope) ----
    char* WS  = (char*)d_ws;
    char* BIG = WS;                          // [0, 16,777,216)
    int*  flag = (int*)(WS + 16777216);
    float* WB  = (float*)(WS + 16777728);
    const int O_E1W = 0;
    const int O_E1B = 1024;
    const int O_E2W = 1040;
    const int O_E2B = 33808;
    const int O_E3W = 33840;
    const int O_E3B = 164912;
    const int O_CB  = 164976;
    const int O_D1W = 197744;
    const int O_D1B = 328816;
    const int O_D2W = 328848;
    const int O_D2B = 361616;
    const int O_D3W = 361632;
    const int O_D3B = 362656;
    const int O_CN  = 362660;                // ws ends 18,230,416 B

    // ---- d_out: f32[9,453,568] ----
    float* OF = (float*)d_out;
    float* xhat  = OF;
    float* quant = OF + 8388608;
    float* idxf  = OF + 9437184;
    float* h1     = OF;                      // [0, 8388608)  encode (PAIR of samples)
    float* z_all  = OF;                      // [0, 1048576)  encode (h1 dead by enc3)
    float* g1_all = OF + 4194304;            // [4194304, 8388608) decode
    float* wr1 = OF + 8388608;
    float* wr2 = OF + 8519680;
    float* wr3 = OF + 8552448;
    float* h2_all = (float*)BIG;
    bf*    g2     = (bf*)BIG;

    auto nb = [](long long t) { return (unsigned)((t + 255) / 256); };

    // ---- detect + convert + prep ----
    k_detect<<<dim3(1), 256, 0, stream>>>((const unsigned short*)d_in[0], flag);
    SrcPtrs sp;
    for (int i = 0; i < 13; ++i) sp.p[i] = d_in[i + 1];
    k_cvtall<<<nb(362657), 256, 0, stream>>>(sp, WB, flag);
    k_cnorm<<<dim3(2), 256, 0, stream>>>(WB + O_CB, WB + O_CN);
    k_rearr<<<dim3(512), 256, 0, stream>>>(WB + O_D1W, wr1, 64, 32);
    k_rearr<<<dim3(128), 256, 0, stream>>>(WB + O_D2W, wr2, 32, 16);
    k_rearr<<<dim3(4),   256, 0, stream>>>(WB + O_D3W, wr3, 16, 1);

    // ---- encode (pair-batched) ----
    for (int p = 0; p < 2; ++p) {
        k_enc1<<<dim3(1024, 2), 256, 0, stream>>>(d_in[0], flag,
            (long long)p * 2 * 2097152, WB + O_E1W, WB + O_E1B, h1);
        k_enc2<<<dim3(128, 4, 2), 256, 0, stream>>>(h1, WB + O_E2W, WB + O_E2B,
            h2_all + (size_t)p * 2 * 1048576);
    }
    k_enc3<<<dim3(16, 16, 4), 256, 0, stream>>>(h2_all, WB + O_E3W, WB + O_E3B, z_all);
    k_vq<<<dim3(256), 256, 0, stream>>>(z_all, WB + O_CB, WB + O_CN, idxf);

    // ---- decode (dec1 gathers codebook directly via idx) ----
    k_dec1<<<dim3(16, 8, 8), 256, 0, stream>>>(idxf, WB + O_CB, wr1,
        WB + O_D1B, g1_all);
    for (int h = 0; h < 2; ++h) {
        k_dec2<<<dim3(128, 8, 2), 256, 0, stream>>>(g1_all + (size_t)h * 2097152,
            wr2, WB + O_D2B, g2);
        k_dec3<<<dim3(16, 64, 2), 256, 0, stream>>>(g2, wr3, WB + O_D3B,
            xhat + (size_t)h * 4194304);
    }

    // ---- final quant gather (overwrites wr scratch) ----
    k_gather<<<nb(1048576LL), 256, 0, stream>>>(idxf, WB + O_CB, quant);
}

// Round 22
// 736.813 us; speedup vs baseline: 1.3441x; 1.1434x over previous
//
#include <hip/hip_runtime.h>
#include <hip/hip_bf16.h>

// ---------------------------------------------------------------------------
// VQ-VAE 3D forward (bc=16, ld=64, ne=512).  d_out = f32[9,453,568]:
//   xhat [0,8388608) | quant [8388608,9437184) | idx [9437184,9453568)
// ws (<=18,230,416 B proven): BIG [0,16,777,216) | flag | WB f32 weights+cn.
//
// Round-22: byte-exact REVERT to the round-18 kernel (737.9 us, session best).
// r19 (+0), r20 (-252), r21 (-104) all failed to beat it:
//   r20: double-stage enc2 -> VGPR/LDS occupancy drop + L2 thrash.
//   r21: gather-fused dec1 -> uncoalesced per-lane codebook walks (206 us).
// Rule bank: (1) block count / occupancy dominates per-thread cleverness;
// (2) keep codebook reads coalesced via the staging gather; (3) enc2/enc3
// prefetch+LDS shapes are at their local optima.
// ---------------------------------------------------------------------------

typedef __hip_bfloat16 bf;
__device__ inline float b2f(bf v) { return __bfloat162float(v); }

// ---------- dtype detect ------------------------------------------------------
__global__ __launch_bounds__(256) void k_detect(const unsigned short* xu, int* flag)
{
    __shared__ int cnt[256];
    int t = threadIdx.x, c = 0;
    for (int i = t; i < 4096; i += 256) {
        unsigned short v = xu[i];
        int e = (v >> 7) & 0xFF;
        if (v == 0 || (e >= 100 && e <= 140)) c++;
    }
    cnt[t] = c;
    __syncthreads();
    for (int o = 128; o > 0; o >>= 1) { if (t < o) cnt[t] += cnt[t + o]; __syncthreads(); }
    if (t == 0) *flag = (cnt[0] >= 3277) ? 1 : 0;
}

// ---------- fused param convert (13 tensors -> contiguous WB) -----------------
struct SrcPtrs { const void* p[13]; };
__global__ __launch_bounds__(256) void k_cvtall(SrcPtrs sp, float* __restrict__ WB,
                                                const int* flag)
{
    const int offs[14] = {0,1024,1040,33808,33840,164912,164976,197744,
                          328816,328848,361616,361632,362656,362657};
    int gid = blockIdx.x * 256 + threadIdx.x;
    if (gid >= 362657) return;
    int j = 0;
    #pragma unroll
    for (int s = 1; s < 13; ++s) if (gid >= offs[s]) j = s;
    int rel = gid - offs[j];
    float v = (*flag) ? b2f(((const bf*)sp.p[j])[rel])
                      : ((const float*)sp.p[j])[rel];
    WB[gid] = v;
}

// ---------- deconv weight rearrange: w[ci][co][4,4,4] -> wr[p][ci][co][8] -----
__global__ __launch_bounds__(256) void k_rearr(const float* __restrict__ w,
    float* __restrict__ wr, int Cin, int Cout)
{
    int id = blockIdx.x * 256 + threadIdx.x;
    int total = 8 * Cin * Cout * 8;
    if (id >= total) return;
    int tap = id & 7;
    int wi = tap & 1, hi = (tap >> 1) & 1, di = (tap >> 2) & 1;
    int rest = id >> 3;
    int co = rest % Cout;
    int rest2 = rest / Cout;
    int ci = rest2 % Cin;
    int p = rest2 / Cin;
    int pw = p & 1, ph = (p >> 1) & 1, pd = (p >> 2) & 1;
    wr[id] = w[(ci * Cout + co) * 64 + ((1 - pd) + 2 * di) * 16
               + ((1 - ph) + 2 * hi) * 4 + ((1 - pw) + 2 * wi)];
}

// ---------- enc1 (pair-batched): x -> h1[j], relu. grid(1024,2) ---------------
__global__ __launch_bounds__(256) void k_enc1(const void* x, const int* flag,
    long long pairOff, const float* __restrict__ w, const float* __restrict__ b,
    float* __restrict__ out)
{
    int sp = blockIdx.x * 256 + threadIdx.x;
    int j = blockIdx.y;
    int ow = sp & 63, oh = (sp >> 6) & 63, od = sp >> 12;
    const int isBf = *flag;
    const long long nOff = pairOff + (long long)j * 2097152;
    const bf*    xb = (const bf*)x + nOff;
    const float* xf = (const float*)x + nOff;

    float v[64];
    #pragma unroll
    for (int kd = 0; kd < 4; ++kd) {
        int id = 2 * od - 1 + kd;
        #pragma unroll
        for (int kh = 0; kh < 4; ++kh) {
            int ih = 2 * oh - 1 + kh;
            #pragma unroll
            for (int kw = 0; kw < 4; ++kw) {
                int iw = 2 * ow - 1 + kw;
                bool ok = (unsigned)id < 128u && (unsigned)ih < 128u && (unsigned)iw < 128u;
                long long idx = ((long long)(ok ? id : 0) * 128 + (ok ? ih : 0)) * 128 + (ok ? iw : 0);
                float val = isBf ? b2f(xb[idx]) : xf[idx];
                v[kd * 16 + kh * 4 + kw] = ok ? val : 0.f;
            }
        }
    }
    float* on = out + (size_t)j * 4194304 + sp;
    #pragma unroll
    for (int co = 0; co < 16; ++co) {
        float acc = b[co];
        const float* wp = w + co * 64;
        #pragma unroll
        for (int t = 0; t < 64; ++t) acc += v[t] * wp[t];
        on[(long long)co * 262144] = fmaxf(acc, 0.f);
    }
}

// ---------- enc2 (pair-batched, LDS stride 66, prefetch). grid(128,4,2) -------
__global__ __launch_bounds__(256) void k_enc2(const float* __restrict__ in,
    const float* __restrict__ w, const float* __restrict__ b,
    float* __restrict__ out)
{
    __shared__ __align__(16) float sm[4][18][66];   // stride 66 = 2 mod 32
    const int t = threadIdx.x;
    const int ow = t & 31, ohl = t >> 5;
    const int od = blockIdx.x >> 2;
    const int oh0 = (blockIdx.x & 3) * 8;
    const int cog = blockIdx.y;                  // 4 groups of 8 co
    const int j = blockIdx.z;                    // sample within pair

    { float* s = &sm[0][0][0];
      for (int i = t; i < 4 * 18 * 66; i += 256) s[i] = 0.f; }

    float acc[8];
    #pragma unroll
    for (int u = 0; u < 8; ++u) acc[u] = b[cog * 8 + u];
    const float* gin = in + (size_t)j * 4194304;
    const float* wb = w + (size_t)(cog * 8) * 1024;   // (co*16+ci)*64

    float4 pref[5];
    auto LOADCI = [&](int ci) {
        const float* gci = gin + (size_t)ci * 262144;
        #pragma unroll
        for (int r = 0; r < 5; ++r) {
            int q = r * 256 + t;
            float4 v4 = {0.f, 0.f, 0.f, 0.f};
            if (q < 1152) {
                int kd = q / 288, rem = q % 288;
                int rr = rem / 16, c4 = rem % 16;
                int id = 2 * od - 1 + kd;
                int ih = 2 * oh0 - 1 + rr;
                if ((unsigned)id < 64u && (unsigned)ih < 64u)
                    v4 = *reinterpret_cast<const float4*>(
                        gci + (size_t)id * 4096 + ih * 64 + c4 * 4);
            }
            pref[r] = v4;
        }
    };

    LOADCI(0);
    for (int ci = 0; ci < 16; ++ci) {
        __syncthreads();
        #pragma unroll
        for (int r = 0; r < 5; ++r) {
            int q = r * 256 + t;
            if (q < 1152) {
                int kd = q / 288, rem = q % 288;
                int rr = rem / 16, c4 = rem % 16;
                float* dst = &sm[kd][rr][c4 * 4 + 1];
                dst[0] = pref[r].x; dst[1] = pref[r].y;
                dst[2] = pref[r].z; dst[3] = pref[r].w;
            }
        }
        if (ci + 1 < 16) LOADCI(ci + 1);
        __syncthreads();
        const float* wp = wb + ci * 64;
        #pragma unroll
        for (int kd = 0; kd < 4; ++kd)
            #pragma unroll
            for (int kh = 0; kh < 4; ++kh) {
                const float* row = &sm[kd][2 * ohl + kh][2 * ow];
                float2 r0 = *reinterpret_cast<const float2*>(row);
                float2 r1 = *reinterpret_cast<const float2*>(row + 2);
                float lv[4] = {r0.x, r0.y, r1.x, r1.y};
                #pragma unroll
                for (int kw = 0; kw < 4; ++kw) {
                    int tap = kd * 16 + kh * 4 + kw;
                    #pragma unroll
                    for (int u = 0; u < 8; ++u)
                        acc[u] += lv[kw] * wp[u * 1024 + tap];
                }
            }
    }

    float* on = out + (size_t)j * 1048576 + (size_t)od * 1024 + (oh0 + ohl) * 32 + ow;
    #pragma unroll
    for (int u = 0; u < 8; ++u)
        on[(size_t)(cog * 8 + u) * 32768] = fmaxf(acc[u], 0.f);
}

// ---------- enc3 (LDS stride 38, acc[4], prefetch). grid(16,16,4) -------------
__global__ __launch_bounds__(256) void k_enc3(const float* __restrict__ in,
    const float* __restrict__ w, const float* __restrict__ b,
    float* __restrict__ out)
{
    __shared__ __align__(16) float sm[4][34][38];   // stride 38 = 6 mod 32
    const int t = threadIdx.x;
    const int ow = t & 15, oh = t >> 4;
    const int od = blockIdx.x;
    const int cog = blockIdx.y;                  // 16 groups of 4 co
    const int n = blockIdx.z;

    { float* s = &sm[0][0][0];
      for (int i = t; i < 4 * 34 * 38; i += 256) s[i] = 0.f; }

    float acc[4];
    #pragma unroll
    for (int u = 0; u < 4; ++u) acc[u] = b[cog * 4 + u];
    const float* gin = in + (size_t)n * 1048576;
    const float* wb = w + (size_t)(cog * 4) * 2048;   // (co*32+ci)*64

    const int hh = t >> 3, c4 = t & 7;                // hh 0..31, c4 0..7
    float4 pref[4];
    auto LOADCI = [&](int ci) {
        const float* gci = gin + (size_t)ci * 32768;
        #pragma unroll
        for (int r = 0; r < 4; ++r) {
            int id = 2 * od - 1 + r;
            float4 v4 = {0.f, 0.f, 0.f, 0.f};
            if ((unsigned)id < 32u)
                v4 = *reinterpret_cast<const float4*>(
                    gci + (size_t)id * 1024 + hh * 32 + c4 * 4);
            pref[r] = v4;
        }
    };

    LOADCI(0);
    for (int ci = 0; ci < 32; ++ci) {
        __syncthreads();
        #pragma unroll
        for (int r = 0; r < 4; ++r) {
            float* dst = &sm[r][hh + 1][c4 * 4 + 1];
            dst[0] = pref[r].x; dst[1] = pref[r].y;
            dst[2] = pref[r].z; dst[3] = pref[r].w;
        }
        if (ci + 1 < 32) LOADCI(ci + 1);
        __syncthreads();
        const float* wp = wb + ci * 64;
        #pragma unroll
        for (int kd = 0; kd < 4; ++kd)
            #pragma unroll
            for (int kh = 0; kh < 4; ++kh) {
                const float* row = &sm[kd][2 * oh + kh][2 * ow];
                float2 r0 = *reinterpret_cast<const float2*>(row);
                float2 r1 = *reinterpret_cast<const float2*>(row + 2);
                float lv[4] = {r0.x, r0.y, r1.x, r1.y};
                #pragma unroll
                for (int kw = 0; kw < 4; ++kw) {
                    int tap = kd * 16 + kh * 4 + kw;
                    #pragma unroll
                    for (int u = 0; u < 4; ++u)
                        acc[u] += lv[kw] * wp[u * 2048 + tap];
                }
            }
    }

    float* on = out + (size_t)n * 262144 + (size_t)od * 256 + oh * 16 + ow;
    #pragma unroll
    for (int u = 0; u < 4; ++u)
        on[(size_t)(cog * 4 + u) * 4096] = acc[u];
}

// ---------- codebook norms ----------------------------------------------------
__global__ __launch_bounds__(256) void k_cnorm(const float* __restrict__ cbf,
    float* __restrict__ cn)
{
    int k = blockIdx.x * 256 + threadIdx.x;
    if (k >= 512) return;
    const float* cp = cbf + k * 64;
    float s = 0.f;
    #pragma unroll
    for (int d = 0; d < 64; ++d) s += cp[d] * cp[d];
    cn[k] = s;
}

// ---------- VQ (GEMM-tiled): 64 pos/block, argmin over 512 codes --------------
__global__ __launch_bounds__(256) void k_vq(const float* __restrict__ z,
    const float* __restrict__ cbf, const float* __restrict__ cn,
    float* __restrict__ idxf)
{
    __shared__ __align__(16) float zt[64][68];
    __shared__ __align__(16) float ct[64][68];
    __shared__ float rv[16][64];
    __shared__ int   ri[16][64];

    const int tid = threadIdx.x;
    const int tx = tid & 15, ty = tid >> 4;
    const int p0 = tx * 4, c0 = ty * 4;
    const int pos0 = blockIdx.x * 64;
    const int n = pos0 >> 12, s0 = pos0 & 4095;
    const float* zn = z + (size_t)n * 262144 + s0;

    {
        int p = tid & 63;
        #pragma unroll
        for (int r = 0; r < 16; ++r) {
            int d = (tid >> 6) + r * 4;
            zt[d][p] = zn[(size_t)d * 4096 + p];
        }
    }

    float minv[4] = {3.4e38f, 3.4e38f, 3.4e38f, 3.4e38f};
    int   mini[4] = {0, 0, 0, 0};

    for (int kt = 0; kt < 8; ++kt) {
        const int k0 = kt * 64;
        __syncthreads();
        {
            int kl = tid & 63, quad = tid >> 6;
            #pragma unroll
            for (int r = 0; r < 4; ++r) {
                int d0 = quad * 16 + r * 4;
                float4 v4 = *reinterpret_cast<const float4*>(
                    cbf + (size_t)(k0 + kl) * 64 + d0);
                ct[d0 + 0][kl] = v4.x; ct[d0 + 1][kl] = v4.y;
                ct[d0 + 2][kl] = v4.z; ct[d0 + 3][kl] = v4.w;
            }
        }
        __syncthreads();

        float acc[4][4] = {};
        #pragma unroll 8
        for (int d = 0; d < 64; ++d) {
            float4 za = *reinterpret_cast<const float4*>(&zt[d][p0]);
            float4 ca = *reinterpret_cast<const float4*>(&ct[d][c0]);
            acc[0][0] += za.x * ca.x; acc[0][1] += za.x * ca.y;
            acc[0][2] += za.x * ca.z; acc[0][3] += za.x * ca.w;
            acc[1][0] += za.y * ca.x; acc[1][1] += za.y * ca.y;
            acc[1][2] += za.y * ca.z; acc[1][3] += za.y * ca.w;
            acc[2][0] += za.z * ca.x; acc[2][1] += za.z * ca.y;
            acc[2][2] += za.z * ca.z; acc[2][3] += za.z * ca.w;
            acc[3][0] += za.w * ca.x; acc[3][1] += za.w * ca.y;
            acc[3][2] += za.w * ca.z; acc[3][3] += za.w * ca.w;
        }
        #pragma unroll
        for (int jj = 0; jj < 4; ++jj) {
            float cnv = cn[k0 + c0 + jj];
            #pragma unroll
            for (int i = 0; i < 4; ++i) {
                float d2 = cnv - 2.f * acc[i][jj];
                if (d2 < minv[i]) { minv[i] = d2; mini[i] = k0 + c0 + jj; }
            }
        }
    }

    __syncthreads();
    #pragma unroll
    for (int i = 0; i < 4; ++i) { rv[ty][p0 + i] = minv[i]; ri[ty][p0 + i] = mini[i]; }
    __syncthreads();
    if (tid < 64) {
        float bv = rv[0][tid]; int bi = ri[0][tid];
        for (int g = 1; g < 16; ++g) {
            float vv = rv[g][tid]; int ii = ri[g][tid];
            if (vv < bv || (vv == bv && ii < bi)) { bv = vv; bi = ii; }
        }
        idxf[pos0 + tid] = (float)bi;
    }
}

// ---------- gather codebook rows ----------------------------------------------
__global__ __launch_bounds__(256) void k_gather(const float* __restrict__ idxf,
    const float* __restrict__ cbf, float* __restrict__ q)
{
    long long i = (long long)blockIdx.x * 256 + threadIdx.x;   // [n][d][s]
    if (i >= 1048576LL) return;
    int s = (int)(i & 4095);
    int d = (int)((i >> 12) & 63);
    int n = (int)(i >> 18);
    int k = (int)idxf[n * 4096 + s] & 511;
    q[i] = cbf[k * 64 + d];
}

// ---------- dec1 (batched): qf32 -> g1_all, relu. grid(16,8,8) ----------------
__global__ __launch_bounds__(256) void k_dec1(const float* __restrict__ in,
    const float* __restrict__ wr, const float* __restrict__ b,
    float* __restrict__ out)
{
    const int a_w = threadIdx.x & 15;
    const int a_h = threadIdx.x >> 4;
    const int a_d = blockIdx.x;
    const int par = blockIdx.y;
    const int n   = blockIdx.z >> 1;
    const int cog = blockIdx.z & 1;
    const int pd = (par >> 2) & 1, ph = (par >> 1) & 1, pw = par & 1;

    int off[8]; float msk[8];
    #pragma unroll
    for (int di = 0; di < 2; ++di)
        #pragma unroll
        for (int hi = 0; hi < 2; ++hi)
            #pragma unroll
            for (int wi = 0; wi < 2; ++wi) {
                int tt = di * 4 + hi * 2 + wi;
                int id = a_d + pd - di; bool okd = (unsigned)id < 16u; int idc = okd ? id : 0;
                int ih = a_h + ph - hi; bool okh = (unsigned)ih < 16u; int ihc = okh ? ih : 0;
                int iw = a_w + pw - wi; bool okw = (unsigned)iw < 16u; int iwc = okw ? iw : 0;
                off[tt] = (idc * 16 + ihc) * 16 + iwc;
                msk[tt] = (okd && okh && okw) ? 1.f : 0.f;
            }

    float acc[16];
    #pragma unroll
    for (int u = 0; u < 16; ++u) acc[u] = b[cog * 16 + u];

    const float* gin = in + (size_t)n * 262144;
    const float* wp = wr + (size_t)par * 16384 + cog * 128;
    for (int ci = 0; ci < 64; ++ci) {
        const float* base = gin + (size_t)ci * 4096;
        float qv[8];
        #pragma unroll
        for (int tt = 0; tt < 8; ++tt) qv[tt] = base[off[tt]] * msk[tt];
        const float* wc = wp + (size_t)ci * 256;
        #pragma unroll
        for (int u = 0; u < 16; ++u)
            #pragma unroll
            for (int tt = 0; tt < 8; ++tt)
                acc[u] += qv[tt] * wc[u * 8 + tt];
    }

    const int od = 2 * a_d + pd, oh = 2 * a_h + ph, ow = 2 * a_w + pw;
    float* on = out + (size_t)n * 1048576 + ((size_t)od * 32 + oh) * 32 + ow;
    #pragma unroll
    for (int u = 0; u < 16; ++u)
        on[(size_t)(cog * 16 + u) * 32768] = fmaxf(acc[u], 0.f);
}

// ---------- dec2 (half-batched): g1 -> g2 bf16, relu. grid(128,8,2) -----------
__global__ __launch_bounds__(256) void k_dec2(const float* __restrict__ inBase,
    const float* __restrict__ wr, const float* __restrict__ b,
    bf* __restrict__ outBase)
{
    const int a_w = threadIdx.x & 31;
    const int a_h = ((blockIdx.x & 3) << 3) + (threadIdx.x >> 5);
    const int a_d = blockIdx.x >> 2;
    const int par = blockIdx.y;
    const int j   = blockIdx.z;
    const int pd = (par >> 2) & 1, ph = (par >> 1) & 1, pw = par & 1;

    int off[8]; float msk[8];
    #pragma unroll
    for (int di = 0; di < 2; ++di)
        #pragma unroll
        for (int hi = 0; hi < 2; ++hi)
            #pragma unroll
            for (int wi = 0; wi < 2; ++wi) {
                int tt = di * 4 + hi * 2 + wi;
                int id = a_d + pd - di; bool okd = (unsigned)id < 32u; int idc = okd ? id : 0;
                int ih = a_h + ph - hi; bool okh = (unsigned)ih < 32u; int ihc = okh ? ih : 0;
                int iw = a_w + pw - wi; bool okw = (unsigned)iw < 32u; int iwc = okw ? iw : 0;
                off[tt] = (idc * 32 + ihc) * 32 + iwc;
                msk[tt] = (okd && okh && okw) ? 1.f : 0.f;
            }

    float acc[16];
    #pragma unroll
    for (int u = 0; u < 16; ++u) acc[u] = b[u];

    const float* gin = inBase + (size_t)j * 1048576;
    const float* wp = wr + (size_t)par * 4096;
    for (int ci = 0; ci < 32; ++ci) {
        const float* base = gin + (size_t)ci * 32768;
        float qv[8];
        #pragma unroll
        for (int tt = 0; tt < 8; ++tt) qv[tt] = base[off[tt]] * msk[tt];
        const float* wc = wp + (size_t)ci * 128;
        #pragma unroll
        for (int u = 0; u < 16; ++u)
            #pragma unroll
            for (int tt = 0; tt < 8; ++tt)
                acc[u] += qv[tt] * wc[u * 8 + tt];
    }

    const int od = 2 * a_d + pd, oh = 2 * a_h + ph, ow = 2 * a_w + pw;
    bf* on = outBase + (size_t)j * 4194304 + ((size_t)od * 64 + oh) * 64 + ow;
    #pragma unroll
    for (int u = 0; u < 16; ++u)
        on[(size_t)u * 262144] = __float2bfloat16(fmaxf(acc[u], 0.f));
}

// ---------- dec3 (half-batched): g2 bf16 -> xhat, sigmoid. grid(16,64,2) ------
__global__ __launch_bounds__(256) void k_dec3(const bf* __restrict__ inBase,
    const float* __restrict__ wr, const float* __restrict__ b,
    float* __restrict__ outBase)
{
    const int a_w = threadIdx.x & 63;
    const int a_h = (blockIdx.x << 2) + (threadIdx.x >> 6);
    const int a_d = blockIdx.y;
    const int j   = blockIdx.z;

    int noff[27]; float nmsk[27];
    #pragma unroll
    for (int dd = -1; dd <= 1; ++dd)
        #pragma unroll
        for (int dh = -1; dh <= 1; ++dh)
            #pragma unroll
            for (int dw = -1; dw <= 1; ++dw) {
                int zd = a_d + dd; bool okd = (unsigned)zd < 64u; int zdc = okd ? zd : 0;
                int zh = a_h + dh; bool okh = (unsigned)zh < 64u; int zhc = okh ? zh : 0;
                int zw = a_w + dw; bool okw = (unsigned)zw < 64u; int zwc = okw ? zw : 0;
                int vi = (dd + 1) * 9 + (dh + 1) * 3 + (dw + 1);
                noff[vi] = (zdc * 64 + zhc) * 64 + zwc;
                nmsk[vi] = (okd && okh && okw) ? 1.f : 0.f;
            }

    float bias = b[0];
    float acc[8];
    #pragma unroll
    for (int p = 0; p < 8; ++p) acc[p] = bias;

    const bf* gin = inBase + (size_t)j * 4194304;
    for (int ci = 0; ci < 16; ++ci) {
        const bf* base = gin + (size_t)ci * 262144;
        float v[27];
        #pragma unroll
        for (int tt = 0; tt < 27; ++tt) v[tt] = b2f(base[noff[tt]]) * nmsk[tt];
        #pragma unroll
        for (int pd = 0; pd < 2; ++pd)
            #pragma unroll
            for (int ph = 0; ph < 2; ++ph)
                #pragma unroll
                for (int pw = 0; pw < 2; ++pw) {
                    int p = pd * 4 + ph * 2 + pw;
                    const float* wc = wr + ((size_t)p * 16 + ci) * 8;
                    #pragma unroll
                    for (int di = 0; di < 2; ++di)
                        #pragma unroll
                        for (int hi = 0; hi < 2; ++hi)
                            #pragma unroll
                            for (int wi = 0; wi < 2; ++wi) {
                                int tap = di * 4 + hi * 2 + wi;
                                int vi = (pd - di + 1) * 9 + (ph - hi + 1) * 3 + (pw - wi + 1);
                                acc[p] += v[vi] * wc[tap];
                            }
                }
    }

    float* outp = outBase + (size_t)j * 2097152;
    #pragma unroll
    for (int pd = 0; pd < 2; ++pd)
        #pragma unroll
        for (int ph = 0; ph < 2; ++ph) {
            int od = 2 * a_d + pd, oh = 2 * a_h + ph;
            float s0v = 1.f / (1.f + __expf(-acc[pd * 4 + ph * 2 + 0]));
            float s1v = 1.f / (1.f + __expf(-acc[pd * 4 + ph * 2 + 1]));
            float2 w2; w2.x = s0v; w2.y = s1v;
            *reinterpret_cast<float2*>(&outp[((size_t)od * 128 + oh) * 128 + 2 * a_w]) = w2;
        }
}

// ---------------------------------------------------------------------------
extern "C" void kernel_launch(void* const* d_in, const int* in_sizes, int n_in,
                              void* d_out, int out_size, void* d_ws, size_t ws_size,
                              hipStream_t stream)
{
    if (n_in < 14) return;

    // ---- ws (proven envelope) ----
    char* WS  = (char*)d_ws;
    char* BIG = WS;                          // [0, 16,777,216)
    int*  flag = (int*)(WS + 16777216);
    float* WB  = (float*)(WS + 16777728);
    const int O_E1W = 0;
    const int O_E1B = 1024;
    const int O_E2W = 1040;
    const int O_E2B = 33808;
    const int O_E3W = 33840;
    const int O_E3B = 164912;
    const int O_CB  = 164976;
    const int O_D1W = 197744;
    const int O_D1B = 328816;
    const int O_D2W = 328848;
    const int O_D2B = 361616;
    const int O_D3W = 361632;
    const int O_D3B = 362656;
    const int O_CN  = 362660;                // ws ends 18,230,416 B

    // ---- d_out: f32[9,453,568] ----
    float* OF = (float*)d_out;
    float* xhat  = OF;
    float* quant = OF + 8388608;
    float* idxf  = OF + 9437184;
    float* h1     = OF;                      // [0, 8388608)  encode (PAIR of samples)
    float* z_all  = OF;                      // [0, 1048576)  encode (h1 dead by enc3)
    float* g1_all = OF + 4194304;            // [4194304, 8388608) decode
    float* wr1 = OF + 8388608;
    float* wr2 = OF + 8519680;
    float* wr3 = OF + 8552448;
    float* h2_all = (float*)BIG;
    float* qf32   = (float*)BIG;
    bf*    g2     = (bf*)BIG;

    auto nb = [](long long t) { return (unsigned)((t + 255) / 256); };

    // ---- detect + convert + prep ----
    k_detect<<<dim3(1), 256, 0, stream>>>((const unsigned short*)d_in[0], flag);
    SrcPtrs sp;
    for (int i = 0; i < 13; ++i) sp.p[i] = d_in[i + 1];
    k_cvtall<<<nb(362657), 256, 0, stream>>>(sp, WB, flag);
    k_cnorm<<<dim3(2), 256, 0, stream>>>(WB + O_CB, WB + O_CN);
    k_rearr<<<dim3(512), 256, 0, stream>>>(WB + O_D1W, wr1, 64, 32);
    k_rearr<<<dim3(128), 256, 0, stream>>>(WB + O_D2W, wr2, 32, 16);
    k_rearr<<<dim3(4),   256, 0, stream>>>(WB + O_D3W, wr3, 16, 1);

    // ---- encode (pair-batched) ----
    for (int p = 0; p < 2; ++p) {
        k_enc1<<<dim3(1024, 2), 256, 0, stream>>>(d_in[0], flag,
            (long long)p * 2 * 2097152, WB + O_E1W, WB + O_E1B, h1);
        k_enc2<<<dim3(128, 4, 2), 256, 0, stream>>>(h1, WB + O_E2W, WB + O_E2B,
            h2_all + (size_t)p * 2 * 1048576);
    }
    k_enc3<<<dim3(16, 16, 4), 256, 0, stream>>>(h2_all, WB + O_E3W, WB + O_E3B, z_all);
    k_vq<<<dim3(256), 256, 0, stream>>>(z_all, WB + O_CB, WB + O_CN, idxf);

    // ---- decode ----
    k_gather<<<nb(1048576LL), 256, 0, stream>>>(idxf, WB + O_CB, qf32);
    k_dec1<<<dim3(16, 8, 8), 256, 0, stream>>>(qf32, wr1, WB + O_D1B, g1_all);
    for (int h = 0; h < 2; ++h) {
        k_dec2<<<dim3(128, 8, 2), 256, 0, stream>>>(g1_all + (size_t)h * 2097152,
            wr2, WB + O_D2B, g2);
        k_dec3<<<dim3(16, 64, 2), 256, 0, stream>>>(g2, wr3, WB + O_D3B,
            xhat + (size_t)h * 4194304);
    }

    // ---- final quant gather (overwrites wr scratch) ----
    k_gather<<<nb(1048576LL), 256, 0, stream>>>(idxf, WB + O_CB, quant);
}

// Round 23
// 732.852 us; speedup vs baseline: 1.3514x; 1.0054x over previous
//
#include <hip/hip_runtime.h>
#include <hip/hip_bf16.h>

// ---------------------------------------------------------------------------
// VQ-VAE 3D forward (bc=16, ld=64, ne=512).  d_out = f32[9,453,568]:
//   xhat [0,8388608) | quant [8388608,9437184) | idx [9437184,9453568)
// ws (<=18,230,416 B proven): BIG [0,16,777,216) | flag | WB f32 weights+cn.
//
// Round-23 (single lever, follows the session's only reliable win-rule:
// MORE BLOCKS): enc2 cog 4->8 (4 co each), grid (128,8,2) = 2048 blocks
// = 8 blocks/CU (LDS 19.5KB x 8 = 156KB fits). acc[8]->acc[4].
// Staging per block unchanged; redundancy x2 is L2-absorbed (h1 resident).
// All else byte-identical to r22 (736.8 us, confirmed stable best).
// ---------------------------------------------------------------------------

typedef __hip_bfloat16 bf;
__device__ inline float b2f(bf v) { return __bfloat162float(v); }

// ---------- dtype detect ------------------------------------------------------
__global__ __launch_bounds__(256) void k_detect(const unsigned short* xu, int* flag)
{
    __shared__ int cnt[256];
    int t = threadIdx.x, c = 0;
    for (int i = t; i < 4096; i += 256) {
        unsigned short v = xu[i];
        int e = (v >> 7) & 0xFF;
        if (v == 0 || (e >= 100 && e <= 140)) c++;
    }
    cnt[t] = c;
    __syncthreads();
    for (int o = 128; o > 0; o >>= 1) { if (t < o) cnt[t] += cnt[t + o]; __syncthreads(); }
    if (t == 0) *flag = (cnt[0] >= 3277) ? 1 : 0;
}

// ---------- fused param convert (13 tensors -> contiguous WB) -----------------
struct SrcPtrs { const void* p[13]; };
__global__ __launch_bounds__(256) void k_cvtall(SrcPtrs sp, float* __restrict__ WB,
                                                const int* flag)
{
    const int offs[14] = {0,1024,1040,33808,33840,164912,164976,197744,
                          328816,328848,361616,361632,362656,362657};
    int gid = blockIdx.x * 256 + threadIdx.x;
    if (gid >= 362657) return;
    int j = 0;
    #pragma unroll
    for (int s = 1; s < 13; ++s) if (gid >= offs[s]) j = s;
    int rel = gid - offs[j];
    float v = (*flag) ? b2f(((const bf*)sp.p[j])[rel])
                      : ((const float*)sp.p[j])[rel];
    WB[gid] = v;
}

// ---------- deconv weight rearrange: w[ci][co][4,4,4] -> wr[p][ci][co][8] -----
__global__ __launch_bounds__(256) void k_rearr(const float* __restrict__ w,
    float* __restrict__ wr, int Cin, int Cout)
{
    int id = blockIdx.x * 256 + threadIdx.x;
    int total = 8 * Cin * Cout * 8;
    if (id >= total) return;
    int tap = id & 7;
    int wi = tap & 1, hi = (tap >> 1) & 1, di = (tap >> 2) & 1;
    int rest = id >> 3;
    int co = rest % Cout;
    int rest2 = rest / Cout;
    int ci = rest2 % Cin;
    int p = rest2 / Cin;
    int pw = p & 1, ph = (p >> 1) & 1, pd = (p >> 2) & 1;
    wr[id] = w[(ci * Cout + co) * 64 + ((1 - pd) + 2 * di) * 16
               + ((1 - ph) + 2 * hi) * 4 + ((1 - pw) + 2 * wi)];
}

// ---------- enc1 (pair-batched): x -> h1[j], relu. grid(1024,2) ---------------
__global__ __launch_bounds__(256) void k_enc1(const void* x, const int* flag,
    long long pairOff, const float* __restrict__ w, const float* __restrict__ b,
    float* __restrict__ out)
{
    int sp = blockIdx.x * 256 + threadIdx.x;
    int j = blockIdx.y;
    int ow = sp & 63, oh = (sp >> 6) & 63, od = sp >> 12;
    const int isBf = *flag;
    const long long nOff = pairOff + (long long)j * 2097152;
    const bf*    xb = (const bf*)x + nOff;
    const float* xf = (const float*)x + nOff;

    float v[64];
    #pragma unroll
    for (int kd = 0; kd < 4; ++kd) {
        int id = 2 * od - 1 + kd;
        #pragma unroll
        for (int kh = 0; kh < 4; ++kh) {
            int ih = 2 * oh - 1 + kh;
            #pragma unroll
            for (int kw = 0; kw < 4; ++kw) {
                int iw = 2 * ow - 1 + kw;
                bool ok = (unsigned)id < 128u && (unsigned)ih < 128u && (unsigned)iw < 128u;
                long long idx = ((long long)(ok ? id : 0) * 128 + (ok ? ih : 0)) * 128 + (ok ? iw : 0);
                float val = isBf ? b2f(xb[idx]) : xf[idx];
                v[kd * 16 + kh * 4 + kw] = ok ? val : 0.f;
            }
        }
    }
    float* on = out + (size_t)j * 4194304 + sp;
    #pragma unroll
    for (int co = 0; co < 16; ++co) {
        float acc = b[co];
        const float* wp = w + co * 64;
        #pragma unroll
        for (int t = 0; t < 64; ++t) acc += v[t] * wp[t];
        on[(long long)co * 262144] = fmaxf(acc, 0.f);
    }
}

// ---------- enc2 (pair-batched, 8 cogs of 4 co, prefetch). grid(128,8,2) ------
__global__ __launch_bounds__(256) void k_enc2(const float* __restrict__ in,
    const float* __restrict__ w, const float* __restrict__ b,
    float* __restrict__ out)
{
    __shared__ __align__(16) float sm[4][18][66];   // stride 66 = 2 mod 32
    const int t = threadIdx.x;
    const int ow = t & 31, ohl = t >> 5;
    const int od = blockIdx.x >> 2;
    const int oh0 = (blockIdx.x & 3) * 8;
    const int cog = blockIdx.y;                  // 8 groups of 4 co
    const int j = blockIdx.z;                    // sample within pair

    { float* s = &sm[0][0][0];
      for (int i = t; i < 4 * 18 * 66; i += 256) s[i] = 0.f; }

    float acc[4];
    #pragma unroll
    for (int u = 0; u < 4; ++u) acc[u] = b[cog * 4 + u];
    const float* gin = in + (size_t)j * 4194304;
    const float* wb = w + (size_t)(cog * 4) * 1024;   // (co*16+ci)*64

    float4 pref[5];
    auto LOADCI = [&](int ci) {
        const float* gci = gin + (size_t)ci * 262144;
        #pragma unroll
        for (int r = 0; r < 5; ++r) {
            int q = r * 256 + t;
            float4 v4 = {0.f, 0.f, 0.f, 0.f};
            if (q < 1152) {
                int kd = q / 288, rem = q % 288;
                int rr = rem / 16, c4 = rem % 16;
                int id = 2 * od - 1 + kd;
                int ih = 2 * oh0 - 1 + rr;
                if ((unsigned)id < 64u && (unsigned)ih < 64u)
                    v4 = *reinterpret_cast<const float4*>(
                        gci + (size_t)id * 4096 + ih * 64 + c4 * 4);
            }
            pref[r] = v4;
        }
    };

    LOADCI(0);
    for (int ci = 0; ci < 16; ++ci) {
        __syncthreads();
        #pragma unroll
        for (int r = 0; r < 5; ++r) {
            int q = r * 256 + t;
            if (q < 1152) {
                int kd = q / 288, rem = q % 288;
                int rr = rem / 16, c4 = rem % 16;
                float* dst = &sm[kd][rr][c4 * 4 + 1];
                dst[0] = pref[r].x; dst[1] = pref[r].y;
                dst[2] = pref[r].z; dst[3] = pref[r].w;
            }
        }
        if (ci + 1 < 16) LOADCI(ci + 1);
        __syncthreads();
        const float* wp = wb + ci * 64;
        #pragma unroll
        for (int kd = 0; kd < 4; ++kd)
            #pragma unroll
            for (int kh = 0; kh < 4; ++kh) {
                const float* row = &sm[kd][2 * ohl + kh][2 * ow];
                float2 r0 = *reinterpret_cast<const float2*>(row);
                float2 r1 = *reinterpret_cast<const float2*>(row + 2);
                float lv[4] = {r0.x, r0.y, r1.x, r1.y};
                #pragma unroll
                for (int kw = 0; kw < 4; ++kw) {
                    int tap = kd * 16 + kh * 4 + kw;
                    #pragma unroll
                    for (int u = 0; u < 4; ++u)
                        acc[u] += lv[kw] * wp[u * 1024 + tap];
                }
            }
    }

    float* on = out + (size_t)j * 1048576 + (size_t)od * 1024 + (oh0 + ohl) * 32 + ow;
    #pragma unroll
    for (int u = 0; u < 4; ++u)
        on[(size_t)(cog * 4 + u) * 32768] = fmaxf(acc[u], 0.f);
}

// ---------- enc3 (LDS stride 38, acc[4], prefetch). grid(16,16,4) -------------
__global__ __launch_bounds__(256) void k_enc3(const float* __restrict__ in,
    const float* __restrict__ w, const float* __restrict__ b,
    float* __restrict__ out)
{
    __shared__ __align__(16) float sm[4][34][38];   // stride 38 = 6 mod 32
    const int t = threadIdx.x;
    const int ow = t & 15, oh = t >> 4;
    const int od = blockIdx.x;
    const int cog = blockIdx.y;                  // 16 groups of 4 co
    const int n = blockIdx.z;

    { float* s = &sm[0][0][0];
      for (int i = t; i < 4 * 34 * 38; i += 256) s[i] = 0.f; }

    float acc[4];
    #pragma unroll
    for (int u = 0; u < 4; ++u) acc[u] = b[cog * 4 + u];
    const float* gin = in + (size_t)n * 1048576;
    const float* wb = w + (size_t)(cog * 4) * 2048;   // (co*32+ci)*64

    const int hh = t >> 3, c4 = t & 7;                // hh 0..31, c4 0..7
    float4 pref[4];
    auto LOADCI = [&](int ci) {
        const float* gci = gin + (size_t)ci * 32768;
        #pragma unroll
        for (int r = 0; r < 4; ++r) {
            int id = 2 * od - 1 + r;
            float4 v4 = {0.f, 0.f, 0.f, 0.f};
            if ((unsigned)id < 32u)
                v4 = *reinterpret_cast<const float4*>(
                    gci + (size_t)id * 1024 + hh * 32 + c4 * 4);
            pref[r] = v4;
        }
    };

    LOADCI(0);
    for (int ci = 0; ci < 32; ++ci) {
        __syncthreads();
        #pragma unroll
        for (int r = 0; r < 4; ++r) {
            float* dst = &sm[r][hh + 1][c4 * 4 + 1];
            dst[0] = pref[r].x; dst[1] = pref[r].y;
            dst[2] = pref[r].z; dst[3] = pref[r].w;
        }
        if (ci + 1 < 32) LOADCI(ci + 1);
        __syncthreads();
        const float* wp = wb + ci * 64;
        #pragma unroll
        for (int kd = 0; kd < 4; ++kd)
            #pragma unroll
            for (int kh = 0; kh < 4; ++kh) {
                const float* row = &sm[kd][2 * oh + kh][2 * ow];
                float2 r0 = *reinterpret_cast<const float2*>(row);
                float2 r1 = *reinterpret_cast<const float2*>(row + 2);
                float lv[4] = {r0.x, r0.y, r1.x, r1.y};
                #pragma unroll
                for (int kw = 0; kw < 4; ++kw) {
                    int tap = kd * 16 + kh * 4 + kw;
                    #pragma unroll
                    for (int u = 0; u < 4; ++u)
                        acc[u] += lv[kw] * wp[u * 2048 + tap];
                }
            }
    }

    float* on = out + (size_t)n * 262144 + (size_t)od * 256 + oh * 16 + ow;
    #pragma unroll
    for (int u = 0; u < 4; ++u)
        on[(size_t)(cog * 4 + u) * 4096] = acc[u];
}

// ---------- codebook norms ----------------------------------------------------
__global__ __launch_bounds__(256) void k_cnorm(const float* __restrict__ cbf,
    float* __restrict__ cn)
{
    int k = blockIdx.x * 256 + threadIdx.x;
    if (k >= 512) return;
    const float* cp = cbf + k * 64;
    float s = 0.f;
    #pragma unroll
    for (int d = 0; d < 64; ++d) s += cp[d] * cp[d];
    cn[k] = s;
}

// ---------- VQ (GEMM-tiled): 64 pos/block, argmin over 512 codes --------------
__global__ __launch_bounds__(256) void k_vq(const float* __restrict__ z,
    const float* __restrict__ cbf, const float* __restrict__ cn,
    float* __restrict__ idxf)
{
    __shared__ __align__(16) float zt[64][68];
    __shared__ __align__(16) float ct[64][68];
    __shared__ float rv[16][64];
    __shared__ int   ri[16][64];

    const int tid = threadIdx.x;
    const int tx = tid & 15, ty = tid >> 4;
    const int p0 = tx * 4, c0 = ty * 4;
    const int pos0 = blockIdx.x * 64;
    const int n = pos0 >> 12, s0 = pos0 & 4095;
    const float* zn = z + (size_t)n * 262144 + s0;

    {
        int p = tid & 63;
        #pragma unroll
        for (int r = 0; r < 16; ++r) {
            int d = (tid >> 6) + r * 4;
            zt[d][p] = zn[(size_t)d * 4096 + p];
        }
    }

    float minv[4] = {3.4e38f, 3.4e38f, 3.4e38f, 3.4e38f};
    int   mini[4] = {0, 0, 0, 0};

    for (int kt = 0; kt < 8; ++kt) {
        const int k0 = kt * 64;
        __syncthreads();
        {
            int kl = tid & 63, quad = tid >> 6;
            #pragma unroll
            for (int r = 0; r < 4; ++r) {
                int d0 = quad * 16 + r * 4;
                float4 v4 = *reinterpret_cast<const float4*>(
                    cbf + (size_t)(k0 + kl) * 64 + d0);
                ct[d0 + 0][kl] = v4.x; ct[d0 + 1][kl] = v4.y;
                ct[d0 + 2][kl] = v4.z; ct[d0 + 3][kl] = v4.w;
            }
        }
        __syncthreads();

        float acc[4][4] = {};
        #pragma unroll 8
        for (int d = 0; d < 64; ++d) {
            float4 za = *reinterpret_cast<const float4*>(&zt[d][p0]);
            float4 ca = *reinterpret_cast<const float4*>(&ct[d][c0]);
            acc[0][0] += za.x * ca.x; acc[0][1] += za.x * ca.y;
            acc[0][2] += za.x * ca.z; acc[0][3] += za.x * ca.w;
            acc[1][0] += za.y * ca.x; acc[1][1] += za.y * ca.y;
            acc[1][2] += za.y * ca.z; acc[1][3] += za.y * ca.w;
            acc[2][0] += za.z * ca.x; acc[2][1] += za.z * ca.y;
            acc[2][2] += za.z * ca.z; acc[2][3] += za.z * ca.w;
            acc[3][0] += za.w * ca.x; acc[3][1] += za.w * ca.y;
            acc[3][2] += za.w * ca.z; acc[3][3] += za.w * ca.w;
        }
        #pragma unroll
        for (int jj = 0; jj < 4; ++jj) {
            float cnv = cn[k0 + c0 + jj];
            #pragma unroll
            for (int i = 0; i < 4; ++i) {
                float d2 = cnv - 2.f * acc[i][jj];
                if (d2 < minv[i]) { minv[i] = d2; mini[i] = k0 + c0 + jj; }
            }
        }
    }

    __syncthreads();
    #pragma unroll
    for (int i = 0; i < 4; ++i) { rv[ty][p0 + i] = minv[i]; ri[ty][p0 + i] = mini[i]; }
    __syncthreads();
    if (tid < 64) {
        float bv = rv[0][tid]; int bi = ri[0][tid];
        for (int g = 1; g < 16; ++g) {
            float vv = rv[g][tid]; int ii = ri[g][tid];
            if (vv < bv || (vv == bv && ii < bi)) { bv = vv; bi = ii; }
        }
        idxf[pos0 + tid] = (float)bi;
    }
}

// ---------- gather codebook rows ----------------------------------------------
__global__ __launch_bounds__(256) void k_gather(const float* __restrict__ idxf,
    const float* __restrict__ cbf, float* __restrict__ q)
{
    long long i = (long long)blockIdx.x * 256 + threadIdx.x;   // [n][d][s]
    if (i >= 1048576LL) return;
    int s = (int)(i & 4095);
    int d = (int)((i >> 12) & 63);
    int n = (int)(i >> 18);
    int k = (int)idxf[n * 4096 + s] & 511;
    q[i] = cbf[k * 64 + d];
}

// ---------- dec1 (batched): qf32 -> g1_all, relu. grid(16,8,8) ----------------
__global__ __launch_bounds__(256) void k_dec1(const float* __restrict__ in,
    const float* __restrict__ wr, const float* __restrict__ b,
    float* __restrict__ out)
{
    const int a_w = threadIdx.x & 15;
    const int a_h = threadIdx.x >> 4;
    const int a_d = blockIdx.x;
    const int par = blockIdx.y;
    const int n   = blockIdx.z >> 1;
    const int cog = blockIdx.z & 1;
    const int pd = (par >> 2) & 1, ph = (par >> 1) & 1, pw = par & 1;

    int off[8]; float msk[8];
    #pragma unroll
    for (int di = 0; di < 2; ++di)
        #pragma unroll
        for (int hi = 0; hi < 2; ++hi)
            #pragma unroll
            for (int wi = 0; wi < 2; ++wi) {
                int tt = di * 4 + hi * 2 + wi;
                int id = a_d + pd - di; bool okd = (unsigned)id < 16u; int idc = okd ? id : 0;
                int ih = a_h + ph - hi; bool okh = (unsigned)ih < 16u; int ihc = okh ? ih : 0;
                int iw = a_w + pw - wi; bool okw = (unsigned)iw < 16u; int iwc = okw ? iw : 0;
                off[tt] = (idc * 16 + ihc) * 16 + iwc;
                msk[tt] = (okd && okh && okw) ? 1.f : 0.f;
            }

    float acc[16];
    #pragma unroll
    for (int u = 0; u < 16; ++u) acc[u] = b[cog * 16 + u];

    const float* gin = in + (size_t)n * 262144;
    const float* wp = wr + (size_t)par * 16384 + cog * 128;
    for (int ci = 0; ci < 64; ++ci) {
        const float* base = gin + (size_t)ci * 4096;
        float qv[8];
        #pragma unroll
        for (int tt = 0; tt < 8; ++tt) qv[tt] = base[off[tt]] * msk[tt];
        const float* wc = wp + (size_t)ci * 256;
        #pragma unroll
        for (int u = 0; u < 16; ++u)
            #pragma unroll
            for (int tt = 0; tt < 8; ++tt)
                acc[u] += qv[tt] * wc[u * 8 + tt];
    }

    const int od = 2 * a_d + pd, oh = 2 * a_h + ph, ow = 2 * a_w + pw;
    float* on = out + (size_t)n * 1048576 + ((size_t)od * 32 + oh) * 32 + ow;
    #pragma unroll
    for (int u = 0; u < 16; ++u)
        on[(size_t)(cog * 16 + u) * 32768] = fmaxf(acc[u], 0.f);
}

// ---------- dec2 (half-batched): g1 -> g2 bf16, relu. grid(128,8,2) -----------
__global__ __launch_bounds__(256) void k_dec2(const float* __restrict__ inBase,
    const float* __restrict__ wr, const float* __restrict__ b,
    bf* __restrict__ outBase)
{
    const int a_w = threadIdx.x & 31;
    const int a_h = ((blockIdx.x & 3) << 3) + (threadIdx.x >> 5);
    const int a_d = blockIdx.x >> 2;
    const int par = blockIdx.y;
    const int j   = blockIdx.z;
    const int pd = (par >> 2) & 1, ph = (par >> 1) & 1, pw = par & 1;

    int off[8]; float msk[8];
    #pragma unroll
    for (int di = 0; di < 2; ++di)
        #pragma unroll
        for (int hi = 0; hi < 2; ++hi)
            #pragma unroll
            for (int wi = 0; wi < 2; ++wi) {
                int tt = di * 4 + hi * 2 + wi;
                int id = a_d + pd - di; bool okd = (unsigned)id < 32u; int idc = okd ? id : 0;
                int ih = a_h + ph - hi; bool okh = (unsigned)ih < 32u; int ihc = okh ? ih : 0;
                int iw = a_w + pw - wi; bool okw = (unsigned)iw < 32u; int iwc = okw ? iw : 0;
                off[tt] = (idc * 32 + ihc) * 32 + iwc;
                msk[tt] = (okd && okh && okw) ? 1.f : 0.f;
            }

    float acc[16];
    #pragma unroll
    for (int u = 0; u < 16; ++u) acc[u] = b[u];

    const float* gin = inBase + (size_t)j * 1048576;
    const float* wp = wr + (size_t)par * 4096;
    for (int ci = 0; ci < 32; ++ci) {
        const float* base = gin + (size_t)ci * 32768;
        float qv[8];
        #pragma unroll
        for (int tt = 0; tt < 8; ++tt) qv[tt] = base[off[tt]] * msk[tt];
        const float* wc = wp + (size_t)ci * 128;
        #pragma unroll
        for (int u = 0; u < 16; ++u)
            #pragma unroll
            for (int tt = 0; tt < 8; ++tt)
                acc[u] += qv[tt] * wc[u * 8 + tt];
    }

    const int od = 2 * a_d + pd, oh = 2 * a_h + ph, ow = 2 * a_w + pw;
    bf* on = outBase + (size_t)j * 4194304 + ((size_t)od * 64 + oh) * 64 + ow;
    #pragma unroll
    for (int u = 0; u < 16; ++u)
        on[(size_t)u * 262144] = __float2bfloat16(fmaxf(acc[u], 0.f));
}

// ---------- dec3 (half-batched): g2 bf16 -> xhat, sigmoid. grid(16,64,2) ------
__global__ __launch_bounds__(256) void k_dec3(const bf* __restrict__ inBase,
    const float* __restrict__ wr, const float* __restrict__ b,
    float* __restrict__ outBase)
{
    const int a_w = threadIdx.x & 63;
    const int a_h = (blockIdx.x << 2) + (threadIdx.x >> 6);
    const int a_d = blockIdx.y;
    const int j   = blockIdx.z;

    int noff[27]; float nmsk[27];
    #pragma unroll
    for (int dd = -1; dd <= 1; ++dd)
        #pragma unroll
        for (int dh = -1; dh <= 1; ++dh)
            #pragma unroll
            for (int dw = -1; dw <= 1; ++dw) {
                int zd = a_d + dd; bool okd = (unsigned)zd < 64u; int zdc = okd ? zd : 0;
                int zh = a_h + dh; bool okh = (unsigned)zh < 64u; int zhc = okh ? zh : 0;
                int zw = a_w + dw; bool okw = (unsigned)zw < 64u; int zwc = okw ? zw : 0;
                int vi = (dd + 1) * 9 + (dh + 1) * 3 + (dw + 1);
                noff[vi] = (zdc * 64 + zhc) * 64 + zwc;
                nmsk[vi] = (okd && okh && okw) ? 1.f : 0.f;
            }

    float bias = b[0];
    float acc[8];
    #pragma unroll
    for (int p = 0; p < 8; ++p) acc[p] = bias;

    const bf* gin = inBase + (size_t)j * 4194304;
    for (int ci = 0; ci < 16; ++ci) {
        const bf* base = gin + (size_t)ci * 262144;
        float v[27];
        #pragma unroll
        for (int tt = 0; tt < 27; ++tt) v[tt] = b2f(base[noff[tt]]) * nmsk[tt];
        #pragma unroll
        for (int pd = 0; pd < 2; ++pd)
            #pragma unroll
            for (int ph = 0; ph < 2; ++ph)
                #pragma unroll
                for (int pw = 0; pw < 2; ++pw) {
                    int p = pd * 4 + ph * 2 + pw;
                    const float* wc = wr + ((size_t)p * 16 + ci) * 8;
                    #pragma unroll
                    for (int di = 0; di < 2; ++di)
                        #pragma unroll
                        for (int hi = 0; hi < 2; ++hi)
                            #pragma unroll
                            for (int wi = 0; wi < 2; ++wi) {
                                int tap = di * 4 + hi * 2 + wi;
                                int vi = (pd - di + 1) * 9 + (ph - hi + 1) * 3 + (pw - wi + 1);
                                acc[p] += v[vi] * wc[tap];
                            }
                }
    }

    float* outp = outBase + (size_t)j * 2097152;
    #pragma unroll
    for (int pd = 0; pd < 2; ++pd)
        #pragma unroll
        for (int ph = 0; ph < 2; ++ph) {
            int od = 2 * a_d + pd, oh = 2 * a_h + ph;
            float s0v = 1.f / (1.f + __expf(-acc[pd * 4 + ph * 2 + 0]));
            float s1v = 1.f / (1.f + __expf(-acc[pd * 4 + ph * 2 + 1]));
            float2 w2; w2.x = s0v; w2.y = s1v;
            *reinterpret_cast<float2*>(&outp[((size_t)od * 128 + oh) * 128 + 2 * a_w]) = w2;
        }
}

// ---------------------------------------------------------------------------
extern "C" void kernel_launch(void* const* d_in, const int* in_sizes, int n_in,
                              void* d_out, int out_size, void* d_ws, size_t ws_size,
                              hipStream_t stream)
{
    if (n_in < 14) return;

    // ---- ws (proven envelope) ----
    char* WS  = (char*)d_ws;
    char* BIG = WS;                          // [0, 16,777,216)
    int*  flag = (int*)(WS + 16777216);
    float* WB  = (float*)(WS + 16777728);
    const int O_E1W = 0;
    const int O_E1B = 1024;
    const int O_E2W = 1040;
    const int O_E2B = 33808;
    const int O_E3W = 33840;
    const int O_E3B = 164912;
    const int O_CB  = 164976;
    const int O_D1W = 197744;
    const int O_D1B = 328816;
    const int O_D2W = 328848;
    const int O_D2B = 361616;
    const int O_D3W = 361632;
    const int O_D3B = 362656;
    const int O_CN  = 362660;                // ws ends 18,230,416 B

    // ---- d_out: f32[9,453,568] ----
    float* OF = (float*)d_out;
    float* xhat  = OF;
    float* quant = OF + 8388608;
    float* idxf  = OF + 9437184;
    float* h1     = OF;                      // [0, 8388608)  encode (PAIR of samples)
    float* z_all  = OF;                      // [0, 1048576)  encode (h1 dead by enc3)
    float* g1_all = OF + 4194304;            // [4194304, 8388608) decode
    float* wr1 = OF + 8388608;
    float* wr2 = OF + 8519680;
    float* wr3 = OF + 8552448;
    float* h2_all = (float*)BIG;
    float* qf32   = (float*)BIG;
    bf*    g2     = (bf*)BIG;

    auto nb = [](long long t) { return (unsigned)((t + 255) / 256); };

    // ---- detect + convert + prep ----
    k_detect<<<dim3(1), 256, 0, stream>>>((const unsigned short*)d_in[0], flag);
    SrcPtrs sp;
    for (int i = 0; i < 13; ++i) sp.p[i] = d_in[i + 1];
    k_cvtall<<<nb(362657), 256, 0, stream>>>(sp, WB, flag);
    k_cnorm<<<dim3(2), 256, 0, stream>>>(WB + O_CB, WB + O_CN);
    k_rearr<<<dim3(512), 256, 0, stream>>>(WB + O_D1W, wr1, 64, 32);
    k_rearr<<<dim3(128), 256, 0, stream>>>(WB + O_D2W, wr2, 32, 16);
    k_rearr<<<dim3(4),   256, 0, stream>>>(WB + O_D3W, wr3, 16, 1);

    // ---- encode (pair-batched) ----
    for (int p = 0; p < 2; ++p) {
        k_enc1<<<dim3(1024, 2), 256, 0, stream>>>(d_in[0], flag,
            (long long)p * 2 * 2097152, WB + O_E1W, WB + O_E1B, h1);
        k_enc2<<<dim3(128, 8, 2), 256, 0, stream>>>(h1, WB + O_E2W, WB + O_E2B,
            h2_all + (size_t)p * 2 * 1048576);
    }
    k_enc3<<<dim3(16, 16, 4), 256, 0, stream>>>(h2_all, WB + O_E3W, WB + O_E3B, z_all);
    k_vq<<<dim3(256), 256, 0, stream>>>(z_all, WB + O_CB, WB + O_CN, idxf);

    // ---- decode ----
    k_gather<<<nb(1048576LL), 256, 0, stream>>>(idxf, WB + O_CB, qf32);
    k_dec1<<<dim3(16, 8, 8), 256, 0, stream>>>(qf32, wr1, WB + O_D1B, g1_all);
    for (int h = 0; h < 2; ++h) {
        k_dec2<<<dim3(128, 8, 2), 256, 0, stream>>>(g1_all + (size_t)h * 2097152,
            wr2, WB + O_D2B, g2);
        k_dec3<<<dim3(16, 64, 2), 256, 0, stream>>>(g2, wr3, WB + O_D3B,
            xhat + (size_t)h * 4194304);
    }

    // ---- final quant gather (overwrites wr scratch) ----
    k_gather<<<nb(1048576LL), 256, 0, stream>>>(idxf, WB + O_CB, quant);
}

// Round 24
// 732.428 us; speedup vs baseline: 1.3522x; 1.0006x over previous
//
#include <hip/hip_runtime.h>
#include <hip/hip_bf16.h>

// ---------------------------------------------------------------------------
// VQ-VAE 3D forward (bc=16, ld=64, ne=512).  d_out = f32[9,453,568]:
//   xhat [0,8388608) | quant [8388608,9437184) | idx [9437184,9453568)
// ws (<=18,230,416 B proven): BIG [0,16,777,216) | flag | WB f32 weights+cn.
//
// Round-24 (single lever): prep phase fused 6 kernels -> 1 (k_prep).
// Each block recomputes the dtype flag locally (L2-hot 8KB scan) so
// cvtall/cnorm/rearr have no inter-block deps and read raw d_in directly.
// Saves 5 launch gaps. All compute/downstream byte-identical to r23 (732.9).
// ---------------------------------------------------------------------------

typedef __hip_bfloat16 bf;
__device__ inline float b2f(bf v) { return __bfloat162float(v); }

struct SrcPtrs { const void* p[13]; };

// ---------- fused prep: detect + cvtall + cnorm + rearr1/2/3. grid(2063) -----
__global__ __launch_bounds__(256) void k_prep(const unsigned short* __restrict__ xu,
    SrcPtrs sp, float* __restrict__ WB, int* __restrict__ flag,
    float* __restrict__ wr1, float* __restrict__ wr2, float* __restrict__ wr3)
{
    __shared__ int cnt[256];
    const int t = threadIdx.x;
    int c = 0;
    for (int i = t; i < 4096; i += 256) {
        unsigned short v = xu[i];
        int e = (v >> 7) & 0xFF;
        if (v == 0 || (e >= 100 && e <= 140)) c++;
    }
    cnt[t] = c;
    __syncthreads();
    for (int o = 128; o > 0; o >>= 1) { if (t < o) cnt[t] += cnt[t + o]; __syncthreads(); }
    const int isBf = (cnt[0] >= 3277) ? 1 : 0;
    if (blockIdx.x == 0 && t == 0) *flag = isBf;

    long long gid = (long long)blockIdx.x * 256 + t;
    auto ldv = [&](const void* p, long long i) -> float {
        return isBf ? b2f(((const bf*)p)[i]) : ((const float*)p)[i];
    };

    if (gid < 362657) {                       // ---- cvtall ----
        const int offs[14] = {0,1024,1040,33808,33840,164912,164976,197744,
                              328816,328848,361616,361632,362656,362657};
        int g = (int)gid;
        int j = 0;
        #pragma unroll
        for (int s = 1; s < 13; ++s) if (g >= offs[s]) j = s;
        WB[g] = ldv(sp.p[j], g - offs[j]);
    } else if (gid < 363169) {                // ---- cnorm (cb = sp.p[6]) ----
        int k = (int)(gid - 362657);
        float s = 0.f;
        #pragma unroll
        for (int d = 0; d < 64; ++d) { float v = ldv(sp.p[6], (long long)k * 64 + d); s += v * v; }
        WB[362660 + k] = s;
    } else if (gid < 494241) {                // ---- rearr1 (d1w = sp.p[7], 64->32) ----
        int id = (int)(gid - 363169);
        int tap = id & 7;
        int wi = tap & 1, hi = (tap >> 1) & 1, di = (tap >> 2) & 1;
        int rest = id >> 3;
        int co = rest & 31;
        int rest2 = rest >> 5;
        int ci = rest2 & 63;
        int p = rest2 >> 6;
        int pw = p & 1, ph = (p >> 1) & 1, pd = (p >> 2) & 1;
        wr1[id] = ldv(sp.p[7], (long long)(ci * 32 + co) * 64
                 + ((1 - pd) + 2 * di) * 16 + ((1 - ph) + 2 * hi) * 4 + ((1 - pw) + 2 * wi));
    } else if (gid < 527009) {                // ---- rearr2 (d2w = sp.p[9], 32->16) ----
        int id = (int)(gid - 494241);
        int tap = id & 7;
        int wi = tap & 1, hi = (tap >> 1) & 1, di = (tap >> 2) & 1;
        int rest = id >> 3;
        int co = rest & 15;
        int rest2 = rest >> 4;
        int ci = rest2 & 31;
        int p = rest2 >> 5;
        int pw = p & 1, ph = (p >> 1) & 1, pd = (p >> 2) & 1;
        wr2[id] = ldv(sp.p[9], (long long)(ci * 16 + co) * 64
                 + ((1 - pd) + 2 * di) * 16 + ((1 - ph) + 2 * hi) * 4 + ((1 - pw) + 2 * wi));
    } else if (gid < 528033) {                // ---- rearr3 (d3w = sp.p[11], 16->1) ----
        int id = (int)(gid - 527009);
        int tap = id & 7;
        int wi = tap & 1, hi = (tap >> 1) & 1, di = (tap >> 2) & 1;
        int rest = id >> 3;                   // co = 0
        int ci = rest & 15;
        int p = rest >> 4;
        int pw = p & 1, ph = (p >> 1) & 1, pd = (p >> 2) & 1;
        wr3[id] = ldv(sp.p[11], (long long)ci * 64
                 + ((1 - pd) + 2 * di) * 16 + ((1 - ph) + 2 * hi) * 4 + ((1 - pw) + 2 * wi));
    }
}

// ---------- enc1 (pair-batched): x -> h1[j], relu. grid(1024,2) ---------------
__global__ __launch_bounds__(256) void k_enc1(const void* x, const int* flag,
    long long pairOff, const float* __restrict__ w, const float* __restrict__ b,
    float* __restrict__ out)
{
    int sp = blockIdx.x * 256 + threadIdx.x;
    int j = blockIdx.y;
    int ow = sp & 63, oh = (sp >> 6) & 63, od = sp >> 12;
    const int isBf = *flag;
    const long long nOff = pairOff + (long long)j * 2097152;
    const bf*    xb = (const bf*)x + nOff;
    const float* xf = (const float*)x + nOff;

    float v[64];
    #pragma unroll
    for (int kd = 0; kd < 4; ++kd) {
        int id = 2 * od - 1 + kd;
        #pragma unroll
        for (int kh = 0; kh < 4; ++kh) {
            int ih = 2 * oh - 1 + kh;
            #pragma unroll
            for (int kw = 0; kw < 4; ++kw) {
                int iw = 2 * ow - 1 + kw;
                bool ok = (unsigned)id < 128u && (unsigned)ih < 128u && (unsigned)iw < 128u;
                long long idx = ((long long)(ok ? id : 0) * 128 + (ok ? ih : 0)) * 128 + (ok ? iw : 0);
                float val = isBf ? b2f(xb[idx]) : xf[idx];
                v[kd * 16 + kh * 4 + kw] = ok ? val : 0.f;
            }
        }
    }
    float* on = out + (size_t)j * 4194304 + sp;
    #pragma unroll
    for (int co = 0; co < 16; ++co) {
        float acc = b[co];
        const float* wp = w + co * 64;
        #pragma unroll
        for (int t = 0; t < 64; ++t) acc += v[t] * wp[t];
        on[(long long)co * 262144] = fmaxf(acc, 0.f);
    }
}

// ---------- enc2 (pair-batched, 8 cogs of 4 co, prefetch). grid(128,8,2) ------
__global__ __launch_bounds__(256) void k_enc2(const float* __restrict__ in,
    const float* __restrict__ w, const float* __restrict__ b,
    float* __restrict__ out)
{
    __shared__ __align__(16) float sm[4][18][66];   // stride 66 = 2 mod 32
    const int t = threadIdx.x;
    const int ow = t & 31, ohl = t >> 5;
    const int od = blockIdx.x >> 2;
    const int oh0 = (blockIdx.x & 3) * 8;
    const int cog = blockIdx.y;                  // 8 groups of 4 co
    const int j = blockIdx.z;                    // sample within pair

    { float* s = &sm[0][0][0];
      for (int i = t; i < 4 * 18 * 66; i += 256) s[i] = 0.f; }

    float acc[4];
    #pragma unroll
    for (int u = 0; u < 4; ++u) acc[u] = b[cog * 4 + u];
    const float* gin = in + (size_t)j * 4194304;
    const float* wb = w + (size_t)(cog * 4) * 1024;   // (co*16+ci)*64

    float4 pref[5];
    auto LOADCI = [&](int ci) {
        const float* gci = gin + (size_t)ci * 262144;
        #pragma unroll
        for (int r = 0; r < 5; ++r) {
            int q = r * 256 + t;
            float4 v4 = {0.f, 0.f, 0.f, 0.f};
            if (q < 1152) {
                int kd = q / 288, rem = q % 288;
                int rr = rem / 16, c4 = rem % 16;
                int id = 2 * od - 1 + kd;
                int ih = 2 * oh0 - 1 + rr;
                if ((unsigned)id < 64u && (unsigned)ih < 64u)
                    v4 = *reinterpret_cast<const float4*>(
                        gci + (size_t)id * 4096 + ih * 64 + c4 * 4);
            }
            pref[r] = v4;
        }
    };

    LOADCI(0);
    for (int ci = 0; ci < 16; ++ci) {
        __syncthreads();
        #pragma unroll
        for (int r = 0; r < 5; ++r) {
            int q = r * 256 + t;
            if (q < 1152) {
                int kd = q / 288, rem = q % 288;
                int rr = rem / 16, c4 = rem % 16;
                float* dst = &sm[kd][rr][c4 * 4 + 1];
                dst[0] = pref[r].x; dst[1] = pref[r].y;
                dst[2] = pref[r].z; dst[3] = pref[r].w;
            }
        }
        if (ci + 1 < 16) LOADCI(ci + 1);
        __syncthreads();
        const float* wp = wb + ci * 64;
        #pragma unroll
        for (int kd = 0; kd < 4; ++kd)
            #pragma unroll
            for (int kh = 0; kh < 4; ++kh) {
                const float* row = &sm[kd][2 * ohl + kh][2 * ow];
                float2 r0 = *reinterpret_cast<const float2*>(row);
                float2 r1 = *reinterpret_cast<const float2*>(row + 2);
                float lv[4] = {r0.x, r0.y, r1.x, r1.y};
                #pragma unroll
                for (int kw = 0; kw < 4; ++kw) {
                    int tap = kd * 16 + kh * 4 + kw;
                    #pragma unroll
                    for (int u = 0; u < 4; ++u)
                        acc[u] += lv[kw] * wp[u * 1024 + tap];
                }
            }
    }

    float* on = out + (size_t)j * 1048576 + (size_t)od * 1024 + (oh0 + ohl) * 32 + ow;
    #pragma unroll
    for (int u = 0; u < 4; ++u)
        on[(size_t)(cog * 4 + u) * 32768] = fmaxf(acc[u], 0.f);
}

// ---------- enc3 (LDS stride 38, acc[4], prefetch). grid(16,16,4) -------------
__global__ __launch_bounds__(256) void k_enc3(const float* __restrict__ in,
    const float* __restrict__ w, const float* __restrict__ b,
    float* __restrict__ out)
{
    __shared__ __align__(16) float sm[4][34][38];   // stride 38 = 6 mod 32
    const int t = threadIdx.x;
    const int ow = t & 15, oh = t >> 4;
    const int od = blockIdx.x;
    const int cog = blockIdx.y;                  // 16 groups of 4 co
    const int n = blockIdx.z;

    { float* s = &sm[0][0][0];
      for (int i = t; i < 4 * 34 * 38; i += 256) s[i] = 0.f; }

    float acc[4];
    #pragma unroll
    for (int u = 0; u < 4; ++u) acc[u] = b[cog * 4 + u];
    const float* gin = in + (size_t)n * 1048576;
    const float* wb = w + (size_t)(cog * 4) * 2048;   // (co*32+ci)*64

    const int hh = t >> 3, c4 = t & 7;                // hh 0..31, c4 0..7
    float4 pref[4];
    auto LOADCI = [&](int ci) {
        const float* gci = gin + (size_t)ci * 32768;
        #pragma unroll
        for (int r = 0; r < 4; ++r) {
            int id = 2 * od - 1 + r;
            float4 v4 = {0.f, 0.f, 0.f, 0.f};
            if ((unsigned)id < 32u)
                v4 = *reinterpret_cast<const float4*>(
                    gci + (size_t)id * 1024 + hh * 32 + c4 * 4);
            pref[r] = v4;
        }
    };

    LOADCI(0);
    for (int ci = 0; ci < 32; ++ci) {
        __syncthreads();
        #pragma unroll
        for (int r = 0; r < 4; ++r) {
            float* dst = &sm[r][hh + 1][c4 * 4 + 1];
            dst[0] = pref[r].x; dst[1] = pref[r].y;
            dst[2] = pref[r].z; dst[3] = pref[r].w;
        }
        if (ci + 1 < 32) LOADCI(ci + 1);
        __syncthreads();
        const float* wp = wb + ci * 64;
        #pragma unroll
        for (int kd = 0; kd < 4; ++kd)
            #pragma unroll
            for (int kh = 0; kh < 4; ++kh) {
                const float* row = &sm[kd][2 * oh + kh][2 * ow];
                float2 r0 = *reinterpret_cast<const float2*>(row);
                float2 r1 = *reinterpret_cast<const float2*>(row + 2);
                float lv[4] = {r0.x, r0.y, r1.x, r1.y};
                #pragma unroll
                for (int kw = 0; kw < 4; ++kw) {
                    int tap = kd * 16 + kh * 4 + kw;
                    #pragma unroll
                    for (int u = 0; u < 4; ++u)
                        acc[u] += lv[kw] * wp[u * 2048 + tap];
                }
            }
    }

    float* on = out + (size_t)n * 262144 + (size_t)od * 256 + oh * 16 + ow;
    #pragma unroll
    for (int u = 0; u < 4; ++u)
        on[(size_t)(cog * 4 + u) * 4096] = acc[u];
}

// ---------- VQ (GEMM-tiled): 64 pos/block, argmin over 512 codes --------------
__global__ __launch_bounds__(256) void k_vq(const float* __restrict__ z,
    const float* __restrict__ cbf, const float* __restrict__ cn,
    float* __restrict__ idxf)
{
    __shared__ __align__(16) float zt[64][68];
    __shared__ __align__(16) float ct[64][68];
    __shared__ float rv[16][64];
    __shared__ int   ri[16][64];

    const int tid = threadIdx.x;
    const int tx = tid & 15, ty = tid >> 4;
    const int p0 = tx * 4, c0 = ty * 4;
    const int pos0 = blockIdx.x * 64;
    const int n = pos0 >> 12, s0 = pos0 & 4095;
    const float* zn = z + (size_t)n * 262144 + s0;

    {
        int p = tid & 63;
        #pragma unroll
        for (int r = 0; r < 16; ++r) {
            int d = (tid >> 6) + r * 4;
            zt[d][p] = zn[(size_t)d * 4096 + p];
        }
    }

    float minv[4] = {3.4e38f, 3.4e38f, 3.4e38f, 3.4e38f};
    int   mini[4] = {0, 0, 0, 0};

    for (int kt = 0; kt < 8; ++kt) {
        const int k0 = kt * 64;
        __syncthreads();
        {
            int kl = tid & 63, quad = tid >> 6;
            #pragma unroll
            for (int r = 0; r < 4; ++r) {
                int d0 = quad * 16 + r * 4;
                float4 v4 = *reinterpret_cast<const float4*>(
                    cbf + (size_t)(k0 + kl) * 64 + d0);
                ct[d0 + 0][kl] = v4.x; ct[d0 + 1][kl] = v4.y;
                ct[d0 + 2][kl] = v4.z; ct[d0 + 3][kl] = v4.w;
            }
        }
        __syncthreads();

        float acc[4][4] = {};
        #pragma unroll 8
        for (int d = 0; d < 64; ++d) {
            float4 za = *reinterpret_cast<const float4*>(&zt[d][p0]);
            float4 ca = *reinterpret_cast<const float4*>(&ct[d][c0]);
            acc[0][0] += za.x * ca.x; acc[0][1] += za.x * ca.y;
            acc[0][2] += za.x * ca.z; acc[0][3] += za.x * ca.w;
            acc[1][0] += za.y * ca.x; acc[1][1] += za.y * ca.y;
            acc[1][2] += za.y * ca.z; acc[1][3] += za.y * ca.w;
            acc[2][0] += za.z * ca.x; acc[2][1] += za.z * ca.y;
            acc[2][2] += za.z * ca.z; acc[2][3] += za.z * ca.w;
            acc[3][0] += za.w * ca.x; acc[3][1] += za.w * ca.y;
            acc[3][2] += za.w * ca.z; acc[3][3] += za.w * ca.w;
        }
        #pragma unroll
        for (int jj = 0; jj < 4; ++jj) {
            float cnv = cn[k0 + c0 + jj];
            #pragma unroll
            for (int i = 0; i < 4; ++i) {
                float d2 = cnv - 2.f * acc[i][jj];
                if (d2 < minv[i]) { minv[i] = d2; mini[i] = k0 + c0 + jj; }
            }
        }
    }

    __syncthreads();
    #pragma unroll
    for (int i = 0; i < 4; ++i) { rv[ty][p0 + i] = minv[i]; ri[ty][p0 + i] = mini[i]; }
    __syncthreads();
    if (tid < 64) {
        float bv = rv[0][tid]; int bi = ri[0][tid];
        for (int g = 1; g < 16; ++g) {
            float vv = rv[g][tid]; int ii = ri[g][tid];
            if (vv < bv || (vv == bv && ii < bi)) { bv = vv; bi = ii; }
        }
        idxf[pos0 + tid] = (float)bi;
    }
}

// ---------- gather codebook rows ----------------------------------------------
__global__ __launch_bounds__(256) void k_gather(const float* __restrict__ idxf,
    const float* __restrict__ cbf, float* __restrict__ q)
{
    long long i = (long long)blockIdx.x * 256 + threadIdx.x;   // [n][d][s]
    if (i >= 1048576LL) return;
    int s = (int)(i & 4095);
    int d = (int)((i >> 12) & 63);
    int n = (int)(i >> 18);
    int k = (int)idxf[n * 4096 + s] & 511;
    q[i] = cbf[k * 64 + d];
}

// ---------- dec1 (batched): qf32 -> g1_all, relu. grid(16,8,8) ----------------
__global__ __launch_bounds__(256) void k_dec1(const float* __restrict__ in,
    const float* __restrict__ wr, const float* __restrict__ b,
    float* __restrict__ out)
{
    const int a_w = threadIdx.x & 15;
    const int a_h = threadIdx.x >> 4;
    const int a_d = blockIdx.x;
    const int par = blockIdx.y;
    const int n   = blockIdx.z >> 1;
    const int cog = blockIdx.z & 1;
    const int pd = (par >> 2) & 1, ph = (par >> 1) & 1, pw = par & 1;

    int off[8]; float msk[8];
    #pragma unroll
    for (int di = 0; di < 2; ++di)
        #pragma unroll
        for (int hi = 0; hi < 2; ++hi)
            #pragma unroll
            for (int wi = 0; wi < 2; ++wi) {
                int tt = di * 4 + hi * 2 + wi;
                int id = a_d + pd - di; bool okd = (unsigned)id < 16u; int idc = okd ? id : 0;
                int ih = a_h + ph - hi; bool okh = (unsigned)ih < 16u; int ihc = okh ? ih : 0;
                int iw = a_w + pw - wi; bool okw = (unsigned)iw < 16u; int iwc = okw ? iw : 0;
                off[tt] = (idc * 16 + ihc) * 16 + iwc;
                msk[tt] = (okd && okh && okw) ? 1.f : 0.f;
            }

    float acc[16];
    #pragma unroll
    for (int u = 0; u < 16; ++u) acc[u] = b[cog * 16 + u];

    const float* gin = in + (size_t)n * 262144;
    const float* wp = wr + (size_t)par * 16384 + cog * 128;
    for (int ci = 0; ci < 64; ++ci) {
        const float* base = gin + (size_t)ci * 4096;
        float qv[8];
        #pragma unroll
        for (int tt = 0; tt < 8; ++tt) qv[tt] = base[off[tt]] * msk[tt];
        const float* wc = wp + (size_t)ci * 256;
        #pragma unroll
        for (int u = 0; u < 16; ++u)
            #pragma unroll
            for (int tt = 0; tt < 8; ++tt)
                acc[u] += qv[tt] * wc[u * 8 + tt];
    }

    const int od = 2 * a_d + pd, oh = 2 * a_h + ph, ow = 2 * a_w + pw;
    float* on = out + (size_t)n * 1048576 + ((size_t)od * 32 + oh) * 32 + ow;
    #pragma unroll
    for (int u = 0; u < 16; ++u)
        on[(size_t)(cog * 16 + u) * 32768] = fmaxf(acc[u], 0.f);
}

// ---------- dec2 (half-batched): g1 -> g2 bf16, relu. grid(128,8,2) -----------
__global__ __launch_bounds__(256) void k_dec2(const float* __restrict__ inBase,
    const float* __restrict__ wr, const float* __restrict__ b,
    bf* __restrict__ outBase)
{
    const int a_w = threadIdx.x & 31;
    const int a_h = ((blockIdx.x & 3) << 3) + (threadIdx.x >> 5);
    const int a_d = blockIdx.x >> 2;
    const int par = blockIdx.y;
    const int j   = blockIdx.z;
    const int pd = (par >> 2) & 1, ph = (par >> 1) & 1, pw = par & 1;

    int off[8]; float msk[8];
    #pragma unroll
    for (int di = 0; di < 2; ++di)
        #pragma unroll
        for (int hi = 0; hi < 2; ++hi)
            #pragma unroll
            for (int wi = 0; wi < 2; ++wi) {
                int tt = di * 4 + hi * 2 + wi;
                int id = a_d + pd - di; bool okd = (unsigned)id < 32u; int idc = okd ? id : 0;
                int ih = a_h + ph - hi; bool okh = (unsigned)ih < 32u; int ihc = okh ? ih : 0;
                int iw = a_w + pw - wi; bool okw = (unsigned)iw < 32u; int iwc = okw ? iw : 0;
                off[tt] = (idc * 32 + ihc) * 32 + iwc;
                msk[tt] = (okd && okh && okw) ? 1.f : 0.f;
            }

    float acc[16];
    #pragma unroll
    for (int u = 0; u < 16; ++u) acc[u] = b[u];

    const float* gin = inBase + (size_t)j * 1048576;
    const float* wp = wr + (size_t)par * 4096;
    for (int ci = 0; ci < 32; ++ci) {
        const float* base = gin + (size_t)ci * 32768;
        float qv[8];
        #pragma unroll
        for (int tt = 0; tt < 8; ++tt) qv[tt] = base[off[tt]] * msk[tt];
        const float* wc = wp + (size_t)ci * 128;
        #pragma unroll
        for (int u = 0; u < 16; ++u)
            #pragma unroll
            for (int tt = 0; tt < 8; ++tt)
                acc[u] += qv[tt] * wc[u * 8 + tt];
    }

    const int od = 2 * a_d + pd, oh = 2 * a_h + ph, ow = 2 * a_w + pw;
    bf* on = outBase + (size_t)j * 4194304 + ((size_t)od * 64 + oh) * 64 + ow;
    #pragma unroll
    for (int u = 0; u < 16; ++u)
        on[(size_t)u * 262144] = __float2bfloat16(fmaxf(acc[u], 0.f));
}

// ---------- dec3 (half-batched): g2 bf16 -> xhat, sigmoid. grid(16,64,2) ------
__global__ __launch_bounds__(256) void k_dec3(const bf* __restrict__ inBase,
    const float* __restrict__ wr, const float* __restrict__ b,
    float* __restrict__ outBase)
{
    const int a_w = threadIdx.x & 63;
    const int a_h = (blockIdx.x << 2) + (threadIdx.x >> 6);
    const int a_d = blockIdx.y;
    const int j   = blockIdx.z;

    int noff[27]; float nmsk[27];
    #pragma unroll
    for (int dd = -1; dd <= 1; ++dd)
        #pragma unroll
        for (int dh = -1; dh <= 1; ++dh)
            #pragma unroll
            for (int dw = -1; dw <= 1; ++dw) {
                int zd = a_d + dd; bool okd = (unsigned)zd < 64u; int zdc = okd ? zd : 0;
                int zh = a_h + dh; bool okh = (unsigned)zh < 64u; int zhc = okh ? zh : 0;
                int zw = a_w + dw; bool okw = (unsigned)zw < 64u; int zwc = okw ? zw : 0;
                int vi = (dd + 1) * 9 + (dh + 1) * 3 + (dw + 1);
                noff[vi] = (zdc * 64 + zhc) * 64 + zwc;
                nmsk[vi] = (okd && okh && okw) ? 1.f : 0.f;
            }

    float bias = b[0];
    float acc[8];
    #pragma unroll
    for (int p = 0; p < 8; ++p) acc[p] = bias;

    const bf* gin = inBase + (size_t)j * 4194304;
    for (int ci = 0; ci < 16; ++ci) {
        const bf* base = gin + (size_t)ci * 262144;
        float v[27];
        #pragma unroll
        for (int tt = 0; tt < 27; ++tt) v[tt] = b2f(base[noff[tt]]) * nmsk[tt];
        #pragma unroll
        for (int pd = 0; pd < 2; ++pd)
            #pragma unroll
            for (int ph = 0; ph < 2; ++ph)
                #pragma unroll
                for (int pw = 0; pw < 2; ++pw) {
                    int p = pd * 4 + ph * 2 + pw;
                    const float* wc = wr + ((size_t)p * 16 + ci) * 8;
                    #pragma unroll
                    for (int di = 0; di < 2; ++di)
                        #pragma unroll
                        for (int hi = 0; hi < 2; ++hi)
                            #pragma unroll
                            for (int wi = 0; wi < 2; ++wi) {
                                int tap = di * 4 + hi * 2 + wi;
                                int vi = (pd - di + 1) * 9 + (ph - hi + 1) * 3 + (pw - wi + 1);
                                acc[p] += v[vi] * wc[tap];
                            }
                }
    }

    float* outp = outBase + (size_t)j * 2097152;
    #pragma unroll
    for (int pd = 0; pd < 2; ++pd)
        #pragma unroll
        for (int ph = 0; ph < 2; ++ph) {
            int od = 2 * a_d + pd, oh = 2 * a_h + ph;
            float s0v = 1.f / (1.f + __expf(-acc[pd * 4 + ph * 2 + 0]));
            float s1v = 1.f / (1.f + __expf(-acc[pd * 4 + ph * 2 + 1]));
            float2 w2; w2.x = s0v; w2.y = s1v;
            *reinterpret_cast<float2*>(&outp[((size_t)od * 128 + oh) * 128 + 2 * a_w]) = w2;
        }
}

// ---------------------------------------------------------------------------
extern "C" void kernel_launch(void* const* d_in, const int* in_sizes, int n_in,
                              void* d_out, int out_size, void* d_ws, size_t ws_size,
                              hipStream_t stream)
{
    if (n_in < 14) return;

    // ---- ws (proven envelope) ----
    char* WS  = (char*)d_ws;
    char* BIG = WS;                          // [0, 16,777,216)
    int*  flag = (int*)(WS + 16777216);
    float* WB  = (float*)(WS + 16777728);
    const int O_E1W = 0;
    const int O_E1B = 1024;
    const int O_E2W = 1040;
    const int O_E2B = 33808;
    const int O_E3W = 33840;
    const int O_E3B = 164912;
    const int O_CB  = 164976;
    const int O_D1B = 328816;
    const int O_D2B = 361616;
    const int O_D3B = 362656;
    const int O_CN  = 362660;                // ws ends 18,230,416 B

    // ---- d_out: f32[9,453,568] ----
    float* OF = (float*)d_out;
    float* xhat  = OF;
    float* quant = OF + 8388608;
    float* idxf  = OF + 9437184;
    float* h1     = OF;                      // [0, 8388608)  encode (PAIR of samples)
    float* z_all  = OF;                      // [0, 1048576)  encode (h1 dead by enc3)
    float* g1_all = OF + 4194304;            // [4194304, 8388608) decode
    float* wr1 = OF + 8388608;
    float* wr2 = OF + 8519680;
    float* wr3 = OF + 8552448;
    float* h2_all = (float*)BIG;
    float* qf32   = (float*)BIG;
    bf*    g2     = (bf*)BIG;

    auto nb = [](long long t) { return (unsigned)((t + 255) / 256); };

    // ---- fused prep (detect + cvtall + cnorm + rearr1/2/3) ----
    SrcPtrs sp;
    for (int i = 0; i < 13; ++i) sp.p[i] = d_in[i + 1];
    k_prep<<<dim3(2063), 256, 0, stream>>>((const unsigned short*)d_in[0],
        sp, WB, flag, wr1, wr2, wr3);

    // ---- encode (pair-batched) ----
    for (int p = 0; p < 2; ++p) {
        k_enc1<<<dim3(1024, 2), 256, 0, stream>>>(d_in[0], flag,
            (long long)p * 2 * 2097152, WB + O_E1W, WB + O_E1B, h1);
        k_enc2<<<dim3(128, 8, 2), 256, 0, stream>>>(h1, WB + O_E2W, WB + O_E2B,
            h2_all + (size_t)p * 2 * 1048576);
    }
    k_enc3<<<dim3(16, 16, 4), 256, 0, stream>>>(h2_all, WB + O_E3W, WB + O_E3B, z_all);
    k_vq<<<dim3(256), 256, 0, stream>>>(z_all, WB + O_CB, WB + O_CN, idxf);

    // ---- decode ----
    k_gather<<<nb(1048576LL), 256, 0, stream>>>(idxf, WB + O_CB, qf32);
    k_dec1<<<dim3(16, 8, 8), 256, 0, stream>>>(qf32, wr1, WB + O_D1B, g1_all);
    for (int h = 0; h < 2; ++h) {
        k_dec2<<<dim3(128, 8, 2), 256, 0, stream>>>(g1_all + (size_t)h * 2097152,
            wr2, WB + O_D2B, g2);
        k_dec3<<<dim3(16, 64, 2), 256, 0, stream>>>(g2, wr3, WB + O_D3B,
            xhat + (size_t)h * 4194304);
    }

    // ---- final quant gather (overwrites wr scratch) ----
    k_gather<<<nb(1048576LL), 256, 0, stream>>>(idxf, WB + O_CB, quant);
}